// Round 1
// baseline (3793.039 us; speedup 1.0000x reference)
//
#include <hip/hip_runtime.h>
#include <cstddef>

#define BN_EPS 1e-5f
constexpr int NNODES = 50000;
constexpr int NEDGES = 640000;
constexpr int DV = 128;          // dim_v == dim_e == 128
constexpr int KE = 384;          // edge MLP input dim
constexpr int KV = 256;          // node MLP input dim
constexpr int TE = 32;           // rows per MLP block
constexpr int NSLOT_E = 512;
constexpr int NSLOT_V = 256;

__device__ __forceinline__ float lrelu(float x) { return x > 0.f ? x : 0.2f * x; }

// LDS-tile x global-weight GEMM: each thread computes 4 rows x 4 cols.
template<int K>
__device__ __forceinline__ void tile_gemm(const float* Xs, const float* __restrict__ W,
                                          int r0, int c0, float acc[4][4]) {
#pragma unroll
  for (int i = 0; i < 4; i++)
#pragma unroll
    for (int c = 0; c < 4; c++) acc[i][c] = 0.f;
#pragma unroll 4
  for (int k = 0; k < K; k++) {
    float4 w = *(const float4*)(W + (size_t)k * DV + c0);
#pragma unroll
    for (int i = 0; i < 4; i++) {
      float x = Xs[(r0 + i) * K + k];
      acc[i][0] = fmaf(x, w.x, acc[i][0]);
      acc[i][1] = fmaf(x, w.y, acc[i][1]);
      acc[i][2] = fmaf(x, w.z, acc[i][2]);
      acc[i][3] = fmaf(x, w.w, acc[i][3]);
    }
  }
}

__global__ __launch_bounds__(256)
void edge_mlp(const float* __restrict__ node_fea, const float* __restrict__ edge_fea,
              const int* __restrict__ idx1, const int* __restrict__ idx2,
              const float* __restrict__ W1, const float* __restrict__ b1,
              const float* __restrict__ W2, const float* __restrict__ b2,
              const float* __restrict__ W3, const float* __restrict__ b3,
              float* __restrict__ h_out, float* __restrict__ slots) {
  __shared__ __align__(16) float zs[TE * KE];   // 48KB, reused as h2 + psq
  __shared__ __align__(16) float h1s[TE * DV];  // 16KB, reused as psum
  const int tid = threadIdx.x;
  const int e0 = blockIdx.x * TE;

  // gather z = [node[idx1] | node[idx2] | edge] : 32 edges x 96 float4
  for (int t = tid; t < TE * 96; t += 256) {
    const int e = t / 96, p = t % 96;
    const int er = e0 + e;
    const float* src;
    if (p < 32)      src = node_fea + (size_t)idx1[er] * DV + p * 4;
    else if (p < 64) src = node_fea + (size_t)idx2[er] * DV + (p - 32) * 4;
    else             src = edge_fea + (size_t)er * DV + (p - 64) * 4;
    *(float4*)&zs[e * KE + p * 4] = *(const float4*)src;
  }
  __syncthreads();

  const int cg = tid & 31, eg = tid >> 5;
  const int c0 = cg * 4, r0 = eg * 4;
  float acc[4][4];

  tile_gemm<KE>(zs, W1, r0, c0, acc);
#pragma unroll
  for (int i = 0; i < 4; i++)
#pragma unroll
    for (int c = 0; c < 4; c++)
      h1s[(r0 + i) * DV + c0 + c] = lrelu(acc[i][c] + b1[c0 + c]);
  __syncthreads();

  tile_gemm<DV>(h1s, W2, r0, c0, acc);
  float* h2s = zs;  // safe: zs last read before previous sync
#pragma unroll
  for (int i = 0; i < 4; i++)
#pragma unroll
    for (int c = 0; c < 4; c++)
      h2s[(r0 + i) * DV + c0 + c] = lrelu(acc[i][c] + b2[c0 + c]);
  __syncthreads();

  tile_gemm<DV>(h2s, W3, r0, c0, acc);
#pragma unroll
  for (int i = 0; i < 4; i++)
#pragma unroll
    for (int c = 0; c < 4; c++) acc[i][c] += b3[c0 + c];

  // store pre-BN h3 into the edge region of d_out (scratch)
#pragma unroll
  for (int i = 0; i < 4; i++) {
    float4 o = make_float4(acc[i][0], acc[i][1], acc[i][2], acc[i][3]);
    *(float4*)&h_out[(size_t)(e0 + r0 + i) * DV + c0] = o;
  }

  // block-partial column sums / sumsq
  __syncthreads();
  float* psum = h1s;  // [8][128]
  float* psq = zs;    // [8][128]
#pragma unroll
  for (int c = 0; c < 4; c++) {
    float s = 0.f, q = 0.f;
#pragma unroll
    for (int i = 0; i < 4; i++) { float v = acc[i][c]; s += v; q += v * v; }
    psum[eg * DV + c0 + c] = s;
    psq[eg * DV + c0 + c] = q;
  }
  __syncthreads();
  if (tid < 128) {
    float s = 0.f, q = 0.f;
#pragma unroll
    for (int g = 0; g < 8; g++) { s += psum[g * DV + tid]; q += psq[g * DV + tid]; }
    float* sl = slots + (size_t)(blockIdx.x % NSLOT_E) * 256;
    atomicAdd(sl + tid, s);
    atomicAdd(sl + 128 + tid, q);
  }
}

__global__ __launch_bounds__(256)
void node_mlp(const float* __restrict__ node_fea,
              const float* __restrict__ accum, const float* __restrict__ cnt,
              const float* __restrict__ W1, const float* __restrict__ b1,
              const float* __restrict__ W2, const float* __restrict__ b2,
              const float* __restrict__ W3, const float* __restrict__ b3,
              float* __restrict__ h_out, float* __restrict__ slots) {
  __shared__ __align__(16) float zs[TE * KV];   // 32KB, reused as h2+psq
  __shared__ __align__(16) float h1s[TE * DV];  // 16KB, reused as psum
  const int tid = threadIdx.x;
  const int n0 = blockIdx.x * TE;

  // gather z2 = [accum/max(cnt,1) | node_fea] : 32 nodes x 64 float4
  for (int t = tid; t < TE * 64; t += 256) {
    const int n = t / 64, p = t % 64;
    const int nr = n0 + n;
    float4 v = make_float4(0.f, 0.f, 0.f, 0.f);
    if (nr < NNODES) {
      if (p < 32) {
        float inv = 1.f / fmaxf(cnt[nr], 1.f);
        float4 a = *(const float4*)(accum + (size_t)nr * DV + p * 4);
        v = make_float4(a.x * inv, a.y * inv, a.z * inv, a.w * inv);
      } else {
        v = *(const float4*)(node_fea + (size_t)nr * DV + (p - 32) * 4);
      }
    }
    *(float4*)&zs[n * KV + p * 4] = v;
  }
  __syncthreads();

  const int cg = tid & 31, eg = tid >> 5;
  const int c0 = cg * 4, r0 = eg * 4;
  float acc[4][4];

  tile_gemm<KV>(zs, W1, r0, c0, acc);
#pragma unroll
  for (int i = 0; i < 4; i++)
#pragma unroll
    for (int c = 0; c < 4; c++)
      h1s[(r0 + i) * DV + c0 + c] = lrelu(acc[i][c] + b1[c0 + c]);
  __syncthreads();

  tile_gemm<DV>(h1s, W2, r0, c0, acc);
  float* h2s = zs;
#pragma unroll
  for (int i = 0; i < 4; i++)
#pragma unroll
    for (int c = 0; c < 4; c++)
      h2s[(r0 + i) * DV + c0 + c] = lrelu(acc[i][c] + b2[c0 + c]);
  __syncthreads();

  tile_gemm<DV>(h2s, W3, r0, c0, acc);
#pragma unroll
  for (int i = 0; i < 4; i++)
#pragma unroll
    for (int c = 0; c < 4; c++) acc[i][c] += b3[c0 + c];

#pragma unroll
  for (int i = 0; i < 4; i++) {
    if (n0 + r0 + i < NNODES) {
      float4 o = make_float4(acc[i][0], acc[i][1], acc[i][2], acc[i][3]);
      *(float4*)&h_out[(size_t)(n0 + r0 + i) * DV + c0] = o;
    }
  }

  __syncthreads();
  float* psum = h1s;
  float* psq = zs;
#pragma unroll
  for (int c = 0; c < 4; c++) {
    float s = 0.f, q = 0.f;
#pragma unroll
    for (int i = 0; i < 4; i++) {
      if (n0 + r0 + i < NNODES) { float v = acc[i][c]; s += v; q += v * v; }
    }
    psum[eg * DV + c0 + c] = s;
    psq[eg * DV + c0 + c] = q;
  }
  __syncthreads();
  if (tid < 128) {
    float s = 0.f, q = 0.f;
#pragma unroll
    for (int g = 0; g < 8; g++) { s += psum[g * DV + tid]; q += psq[g * DV + tid]; }
    float* sl = slots + (size_t)(blockIdx.x % NSLOT_V) * 256;
    atomicAdd(sl + tid, s);
    atomicAdd(sl + 128 + tid, q);
  }
}

// one block, 256 threads: col j total -> scale/shift
__global__ __launch_bounds__(256)
void stats_reduce(const float* __restrict__ slots, int nslot, float inv_n,
                  const float* __restrict__ gamma, const float* __restrict__ beta,
                  float* __restrict__ ss) {
  __shared__ float tot[256];
  const int j = threadIdx.x;
  float s = 0.f;
  for (int t = 0; t < nslot; t++) s += slots[(size_t)t * 256 + j];
  tot[j] = s;
  __syncthreads();
  if (j < 128) {
    float mean = tot[j] * inv_n;
    float var = tot[j + 128] * inv_n - mean * mean;
    float rs = rsqrtf(var + BN_EPS);
    float sc = gamma[j] * rs;
    ss[j] = sc;
    ss[128 + j] = beta[j] - mean * sc;
  }
}

__global__ __launch_bounds__(256)
void edge_finalize(const float* __restrict__ edge_fea, const int* __restrict__ idx1,
                   const float* __restrict__ ss, float* __restrict__ h_inout,
                   float* __restrict__ accum, float* __restrict__ cnt) {
  const int tid = threadIdx.x;
  const int e = blockIdx.x * 8 + (tid >> 5);
  const int j = (tid & 31) * 4;
  const size_t off = (size_t)e * DV + j;
  float4 h = *(float4*)&h_inout[off];
  float4 ef = *(const float4*)&edge_fea[off];
  float e0v = fmaf(h.x, ss[j + 0], ss[128 + j + 0]);
  float e1v = fmaf(h.y, ss[j + 1], ss[128 + j + 1]);
  float e2v = fmaf(h.z, ss[j + 2], ss[128 + j + 2]);
  float e3v = fmaf(h.w, ss[j + 3], ss[128 + j + 3]);
  *(float4*)&h_inout[off] = make_float4(ef.x + e0v, ef.y + e1v, ef.z + e2v, ef.w + e3v);
  const int n = idx1[e];
  float* na = accum + (size_t)n * DV + j;
  atomicAdd(na + 0, e0v);
  atomicAdd(na + 1, e1v);
  atomicAdd(na + 2, e2v);
  atomicAdd(na + 3, e3v);
  if ((tid & 31) == 0) atomicAdd(&cnt[n], 1.f);
}

__global__ __launch_bounds__(256)
void node_finalize(const float* __restrict__ node_fea, const float* __restrict__ ss,
                   float* __restrict__ h_inout) {
  const size_t base = (size_t)blockIdx.x * 1024 + threadIdx.x * 4;
  const int j = (int)(base & 127);
  float4 h = *(float4*)&h_inout[base];
  float4 nf = *(const float4*)&node_fea[base];
  float4 o;
  o.x = nf.x + fmaf(h.x, ss[j + 0], ss[128 + j + 0]);
  o.y = nf.y + fmaf(h.y, ss[j + 1], ss[128 + j + 1]);
  o.z = nf.z + fmaf(h.z, ss[j + 2], ss[128 + j + 2]);
  o.w = nf.w + fmaf(h.w, ss[j + 3], ss[128 + j + 3]);
  *(float4*)&h_inout[base] = o;
}

extern "C" void kernel_launch(void* const* d_in, const int* in_sizes, int n_in,
                              void* d_out, int out_size, void* d_ws, size_t ws_size,
                              hipStream_t stream) {
  const float* node_fea = (const float*)d_in[0];
  const float* edge_fea = (const float*)d_in[1];
  const int* idx1 = (const int*)d_in[2];
  const int* idx2 = (const int*)d_in[3];
  const float* We1 = (const float*)d_in[4];  const float* be1 = (const float*)d_in[5];
  const float* We2 = (const float*)d_in[6];  const float* be2 = (const float*)d_in[7];
  const float* We3 = (const float*)d_in[8];  const float* be3 = (const float*)d_in[9];
  const float* Wv1 = (const float*)d_in[10]; const float* bv1 = (const float*)d_in[11];
  const float* Wv2 = (const float*)d_in[12]; const float* bv2 = (const float*)d_in[13];
  const float* Wv3 = (const float*)d_in[14]; const float* bv3 = (const float*)d_in[15];
  const float* gamma_e = (const float*)d_in[16]; const float* beta_e = (const float*)d_in[17];
  const float* gamma_v = (const float*)d_in[18]; const float* beta_v = (const float*)d_in[19];

  float* out_node = (float*)d_out;                     // [NNODES][128]
  float* out_edge = out_node + (size_t)NNODES * DV;    // [NEDGES][128]

  float* ws = (float*)d_ws;
  size_t o = 0;
  float* accum = ws + o;   o += (size_t)NNODES * DV;   // 25.6MB
  float* cnt = ws + o;     o += NNODES;
  float* slots_e = ws + o; o += (size_t)NSLOT_E * 256;
  float* slots_v = ws + o; o += (size_t)NSLOT_V * 256;
  float* ss_e = ws + o;    o += 256;
  float* ss_v = ws + o;    o += 256;

  // zero accum + cnt + slots each call (harness does not re-poison between replays)
  const size_t zero_bytes =
      ((size_t)NNODES * DV + NNODES + (size_t)NSLOT_E * 256 + (size_t)NSLOT_V * 256) * sizeof(float);
  hipMemsetAsync(d_ws, 0, zero_bytes, stream);

  edge_mlp<<<NEDGES / TE, 256, 0, stream>>>(node_fea, edge_fea, idx1, idx2,
                                            We1, be1, We2, be2, We3, be3,
                                            out_edge, slots_e);
  stats_reduce<<<1, 256, 0, stream>>>(slots_e, NSLOT_E, 1.f / NEDGES, gamma_e, beta_e, ss_e);
  edge_finalize<<<NEDGES / 8, 256, 0, stream>>>(edge_fea, idx1, ss_e, out_edge, accum, cnt);
  node_mlp<<<(NNODES + TE - 1) / TE, 256, 0, stream>>>(node_fea, accum, cnt,
                                                       Wv1, bv1, Wv2, bv2, Wv3, bv3,
                                                       out_node, slots_v);
  stats_reduce<<<1, 256, 0, stream>>>(slots_v, NSLOT_V, 1.f / NNODES, gamma_v, beta_v, ss_v);
  node_finalize<<<(NNODES * DV) / 1024, 256, 0, stream>>>(node_fea, ss_v, out_node);
}

// Round 2
// 2134.856 us; speedup vs baseline: 1.7767x; 1.7767x over previous
//
#include <hip/hip_runtime.h>
#include <cstddef>

#define BN_EPS 1e-5f
constexpr int NNODES = 50000;
constexpr int NEDGES = 640000;
constexpr int DV = 128;
constexpr int NSLOT_E = 512;
constexpr int NSLOT_V = 256;

typedef __attribute__((ext_vector_type(4))) float f32x4;
typedef __attribute__((ext_vector_type(8))) short s16x8;
typedef unsigned short ushort_t;

__device__ __forceinline__ float lrelu(float x) { return x > 0.f ? x : 0.2f * x; }

__device__ __forceinline__ short f2bf(float f) {
  unsigned int u = __builtin_bit_cast(unsigned int, f);
  u += 0x7fffu + ((u >> 16) & 1u);   // round-to-nearest-even
  return (short)(u >> 16);
}

// ---- weight pre-pack: [K][128] f32 -> per-fragment bf16 layout ----
// frag (kk,n): lane holds B[k = kk*32 + (lane>>4)*8 + j][col = n*16 + (lane&15)], j=0..7
__global__ __launch_bounds__(256)
void pack_all(const float* __restrict__ W0, const float* __restrict__ W1,
              const float* __restrict__ W2, const float* __restrict__ W3,
              const float* __restrict__ W4, const float* __restrict__ W5,
              ushort_t* __restrict__ out) {
  int t = blockIdx.x * 256 + threadIdx.x;
  if (t >= 288 * 64) return;
  int lane = t & 63, f = t >> 6;
  const float* W; int lf;
  if (f < 96)       { W = W0; lf = f; }
  else if (f < 128) { W = W1; lf = f - 96; }
  else if (f < 160) { W = W2; lf = f - 128; }
  else if (f < 224) { W = W3; lf = f - 160; }
  else if (f < 256) { W = W4; lf = f - 224; }
  else              { W = W5; lf = f - 256; }
  int kk = lf >> 3, n = lf & 7;
  int k0 = kk * 32 + (lane >> 4) * 8, col = n * 16 + (lane & 15);
  s16x8 v;
#pragma unroll
  for (int j = 0; j < 8; j++) v[j] = f2bf(W[(size_t)(k0 + j) * DV + col]);
  *(s16x8*)(out + (size_t)t * 8) = v;
}

// ---- fused MLP layer: A from swizzled LDS (row stride K*2 B), B frags from global ----
template<int K>
__device__ __forceinline__ void layer_mfma(const char* Als, const s16x8* __restrict__ Wp,
                                           f32x4 acc[8], int lane, int rbase) {
  const int arow = rbase + (lane & 15);
  const int rowoff = arow * (K * 2);
  const int kg16 = (lane >> 4) * 16;
  const int sw = (arow & 7) << 4;
#pragma unroll
  for (int n = 0; n < 8; n++) acc[n] = 0.0f;
#pragma unroll 2
  for (int kk = 0; kk < K / 32; kk++) {
    s16x8 a = *(const s16x8*)(Als + rowoff + ((kk * 64 + kg16) ^ sw));
#pragma unroll
    for (int n = 0; n < 8; n++) {
      s16x8 b = Wp[(kk * 8 + n) * 64 + lane];
      acc[n] = __builtin_amdgcn_mfma_f32_16x16x32_bf16(a, b, acc[n], 0, 0, 0);
    }
  }
}

// bias + lrelu + bf16 -> swizzled LDS (row stride 256B)
__device__ __forceinline__ void store_h_lds(char* H, const f32x4 acc[8],
                                            const float* __restrict__ bias,
                                            int lane, int rbase) {
  const int col0 = lane & 15, rg = lane >> 4;
#pragma unroll
  for (int n = 0; n < 8; n++) {
    float bi = bias[n * 16 + col0];
#pragma unroll
    for (int r = 0; r < 4; r++) {
      int row = rbase + rg * 4 + r;
      float v = lrelu(acc[n][r] + bi);
      *(ushort_t*)(H + row * 256 + ((((n * 16 + col0) * 2)) ^ ((row & 7) << 4))) = (ushort_t)f2bf(v);
    }
  }
}

__global__ __launch_bounds__(256)
void edge_mlp_mfma(const float* __restrict__ node_fea, const float* __restrict__ edge_fea,
                   const int* __restrict__ idx1, const int* __restrict__ idx2,
                   const ushort_t* __restrict__ Wp1, const float* __restrict__ b1,
                   const ushort_t* __restrict__ Wp2, const float* __restrict__ b2,
                   const ushort_t* __restrict__ Wp3, const float* __restrict__ b3,
                   float* __restrict__ h_out, float* __restrict__ slots) {
  __shared__ __align__(16) char zsm[64 * 768];   // z tile (bf16, swizzled), later h2
  __shared__ __align__(16) char hb[64 * 256];    // h1 tile, later BN partials
  const int tid = threadIdx.x;
  const int lane = tid & 63, wid = tid >> 6;
  const int e0 = blockIdx.x * 64;

  // gather z = [node[idx1] | node[idx2] | edge] as bf16 into swizzled LDS
  for (int t = tid; t < 64 * 48; t += 256) {
    int e = t / 48, p = t % 48;
    int er = e0 + e;
    const float* src;
    if (p < 16)      src = node_fea + (size_t)idx1[er] * DV + p * 8;
    else if (p < 32) src = node_fea + (size_t)idx2[er] * DV + (p - 16) * 8;
    else             src = edge_fea + (size_t)er * DV + (p - 32) * 8;
    float4 x0 = *(const float4*)src;
    float4 x1 = *(const float4*)(src + 4);
    s16x8 v;
    v[0] = f2bf(x0.x); v[1] = f2bf(x0.y); v[2] = f2bf(x0.z); v[3] = f2bf(x0.w);
    v[4] = f2bf(x1.x); v[5] = f2bf(x1.y); v[6] = f2bf(x1.z); v[7] = f2bf(x1.w);
    *(s16x8*)(zsm + e * 768 + ((p * 16) ^ ((e & 7) << 4))) = v;
  }
  __syncthreads();

  const int rbase = wid * 16;
  f32x4 acc[8];

  layer_mfma<384>(zsm, (const s16x8*)Wp1, acc, lane, rbase);
  store_h_lds(hb, acc, b1, lane, rbase);
  __syncthreads();

  layer_mfma<128>(hb, (const s16x8*)Wp2, acc, lane, rbase);
  __syncthreads();                 // zsm reads (L1) done everywhere
  store_h_lds(zsm, acc, b2, lane, rbase);
  __syncthreads();

  layer_mfma<128>(zsm, (const s16x8*)Wp3, acc, lane, rbase);

  // epilogue: bias, store pre-BN h3 (f32) to global, BN partial sums
  const int col0 = lane & 15, rg = lane >> 4;
  float* ps = (float*)hb;          // [16][128]
  float* pq = ps + 2048;           // [16][128]
#pragma unroll
  for (int n = 0; n < 8; n++) {
    float bi = b3[n * 16 + col0];
    float s = 0.f, q = 0.f;
#pragma unroll
    for (int r = 0; r < 4; r++) {
      int row = rbase + rg * 4 + r;
      float v = acc[n][r] + bi;
      h_out[(size_t)(e0 + row) * DV + n * 16 + col0] = v;
      s += v; q += v * v;
    }
    ps[(wid * 4 + rg) * DV + n * 16 + col0] = s;
    pq[(wid * 4 + rg) * DV + n * 16 + col0] = q;
  }
  __syncthreads();
  if (tid < 128) {
    float s = 0.f, q = 0.f;
#pragma unroll
    for (int g = 0; g < 16; g++) { s += ps[g * DV + tid]; q += pq[g * DV + tid]; }
    float* sl = slots + (size_t)(blockIdx.x % NSLOT_E) * 256;
    atomicAdd(sl + tid, s);
    atomicAdd(sl + 128 + tid, q);
  }
}

__global__ __launch_bounds__(256)
void node_mlp_mfma(const float* __restrict__ node_fea,
                   const float* __restrict__ accum, const float* __restrict__ cnt,
                   const ushort_t* __restrict__ Wp1, const float* __restrict__ b1,
                   const ushort_t* __restrict__ Wp2, const float* __restrict__ b2,
                   const ushort_t* __restrict__ Wp3, const float* __restrict__ b3,
                   float* __restrict__ h_out, float* __restrict__ slots) {
  __shared__ __align__(16) char zsm[64 * 512];   // z2 tile (bf16, swizzled), later h2
  __shared__ __align__(16) char hb[64 * 256];
  const int tid = threadIdx.x;
  const int lane = tid & 63, wid = tid >> 6;
  const int n0 = blockIdx.x * 64;

  for (int t = tid; t < 64 * 32; t += 256) {
    int e = t / 32, p = t % 32;
    int nr = n0 + e;
    s16x8 v;
    if (nr < NNODES) {
      float4 x0, x1;
      if (p < 16) {
        float inv = 1.f / fmaxf(cnt[nr], 1.f);
        x0 = *(const float4*)(accum + (size_t)nr * DV + p * 8);
        x1 = *(const float4*)(accum + (size_t)nr * DV + p * 8 + 4);
        x0.x *= inv; x0.y *= inv; x0.z *= inv; x0.w *= inv;
        x1.x *= inv; x1.y *= inv; x1.z *= inv; x1.w *= inv;
      } else {
        x0 = *(const float4*)(node_fea + (size_t)nr * DV + (p - 16) * 8);
        x1 = *(const float4*)(node_fea + (size_t)nr * DV + (p - 16) * 8 + 4);
      }
      v[0] = f2bf(x0.x); v[1] = f2bf(x0.y); v[2] = f2bf(x0.z); v[3] = f2bf(x0.w);
      v[4] = f2bf(x1.x); v[5] = f2bf(x1.y); v[6] = f2bf(x1.z); v[7] = f2bf(x1.w);
    } else {
      v = (s16x8)0;
    }
    *(s16x8*)(zsm + e * 512 + ((p * 16) ^ ((e & 7) << 4))) = v;
  }
  __syncthreads();

  const int rbase = wid * 16;
  f32x4 acc[8];

  layer_mfma<256>(zsm, (const s16x8*)Wp1, acc, lane, rbase);
  store_h_lds(hb, acc, b1, lane, rbase);
  __syncthreads();

  layer_mfma<128>(hb, (const s16x8*)Wp2, acc, lane, rbase);
  __syncthreads();
  store_h_lds(zsm, acc, b2, lane, rbase);
  __syncthreads();

  layer_mfma<128>(zsm, (const s16x8*)Wp3, acc, lane, rbase);

  const int col0 = lane & 15, rg = lane >> 4;
  float* ps = (float*)hb;
  float* pq = ps + 2048;
#pragma unroll
  for (int n = 0; n < 8; n++) {
    float bi = b3[n * 16 + col0];
    float s = 0.f, q = 0.f;
#pragma unroll
    for (int r = 0; r < 4; r++) {
      int row = rbase + rg * 4 + r;
      int gr = n0 + row;
      if (gr < NNODES) {
        float v = acc[n][r] + bi;
        h_out[(size_t)gr * DV + n * 16 + col0] = v;
        s += v; q += v * v;
      }
    }
    ps[(wid * 4 + rg) * DV + n * 16 + col0] = s;
    pq[(wid * 4 + rg) * DV + n * 16 + col0] = q;
  }
  __syncthreads();
  if (tid < 128) {
    float s = 0.f, q = 0.f;
#pragma unroll
    for (int g = 0; g < 16; g++) { s += ps[g * DV + tid]; q += pq[g * DV + tid]; }
    float* sl = slots + (size_t)(blockIdx.x % NSLOT_V) * 256;
    atomicAdd(sl + tid, s);
    atomicAdd(sl + 128 + tid, q);
  }
}

__global__ __launch_bounds__(256)
void stats_reduce(const float* __restrict__ slots, int nslot, float inv_n,
                  const float* __restrict__ gamma, const float* __restrict__ beta,
                  float* __restrict__ ss) {
  __shared__ float tot[256];
  const int j = threadIdx.x;
  float s = 0.f;
  for (int t = 0; t < nslot; t++) s += slots[(size_t)t * 256 + j];
  tot[j] = s;
  __syncthreads();
  if (j < 128) {
    float mean = tot[j] * inv_n;
    float var = tot[j + 128] * inv_n - mean * mean;
    float rs = rsqrtf(var + BN_EPS);
    float sc = gamma[j] * rs;
    ss[j] = sc;
    ss[128 + j] = beta[j] - mean * sc;
  }
}

__global__ __launch_bounds__(256)
void edge_finalize(const float* __restrict__ edge_fea, const int* __restrict__ idx1,
                   const float* __restrict__ ss, float* __restrict__ h_inout,
                   float* __restrict__ accum, float* __restrict__ cnt) {
  const int tid = threadIdx.x;
  const int e = blockIdx.x * 8 + (tid >> 5);
  const int j = (tid & 31) * 4;
  const size_t off = (size_t)e * DV + j;
  float4 h = *(float4*)&h_inout[off];
  float4 ef = *(const float4*)&edge_fea[off];
  float e0v = fmaf(h.x, ss[j + 0], ss[128 + j + 0]);
  float e1v = fmaf(h.y, ss[j + 1], ss[128 + j + 1]);
  float e2v = fmaf(h.z, ss[j + 2], ss[128 + j + 2]);
  float e3v = fmaf(h.w, ss[j + 3], ss[128 + j + 3]);
  *(float4*)&h_inout[off] = make_float4(ef.x + e0v, ef.y + e1v, ef.z + e2v, ef.w + e3v);
  const int n = idx1[e];
  float* na = accum + (size_t)n * DV + j;
  atomicAdd(na + 0, e0v);
  atomicAdd(na + 1, e1v);
  atomicAdd(na + 2, e2v);
  atomicAdd(na + 3, e3v);
  if ((tid & 31) == 0) atomicAdd(&cnt[n], 1.f);
}

__global__ __launch_bounds__(256)
void node_finalize(const float* __restrict__ node_fea, const float* __restrict__ ss,
                   float* __restrict__ h_inout) {
  const size_t base = (size_t)blockIdx.x * 1024 + threadIdx.x * 4;
  const int j = (int)(base & 127);
  float4 h = *(float4*)&h_inout[base];
  float4 nf = *(const float4*)&node_fea[base];
  float4 o;
  o.x = nf.x + fmaf(h.x, ss[j + 0], ss[128 + j + 0]);
  o.y = nf.y + fmaf(h.y, ss[j + 1], ss[128 + j + 1]);
  o.z = nf.z + fmaf(h.z, ss[j + 2], ss[128 + j + 2]);
  o.w = nf.w + fmaf(h.w, ss[j + 3], ss[128 + j + 3]);
  *(float4*)&h_inout[base] = o;
}

extern "C" void kernel_launch(void* const* d_in, const int* in_sizes, int n_in,
                              void* d_out, int out_size, void* d_ws, size_t ws_size,
                              hipStream_t stream) {
  const float* node_fea = (const float*)d_in[0];
  const float* edge_fea = (const float*)d_in[1];
  const int* idx1 = (const int*)d_in[2];
  const int* idx2 = (const int*)d_in[3];
  const float* We1 = (const float*)d_in[4];  const float* be1 = (const float*)d_in[5];
  const float* We2 = (const float*)d_in[6];  const float* be2 = (const float*)d_in[7];
  const float* We3 = (const float*)d_in[8];  const float* be3 = (const float*)d_in[9];
  const float* Wv1 = (const float*)d_in[10]; const float* bv1 = (const float*)d_in[11];
  const float* Wv2 = (const float*)d_in[12]; const float* bv2 = (const float*)d_in[13];
  const float* Wv3 = (const float*)d_in[14]; const float* bv3 = (const float*)d_in[15];
  const float* gamma_e = (const float*)d_in[16]; const float* beta_e = (const float*)d_in[17];
  const float* gamma_v = (const float*)d_in[18]; const float* beta_v = (const float*)d_in[19];

  float* out_node = (float*)d_out;                     // [NNODES][128]
  float* out_edge = out_node + (size_t)NNODES * DV;    // [NEDGES][128]

  float* ws = (float*)d_ws;
  size_t o = 0;
  float* accum = ws + o;   o += (size_t)NNODES * DV;
  float* cnt = ws + o;     o += NNODES;
  float* slots_e = ws + o; o += (size_t)NSLOT_E * 256;
  float* slots_v = ws + o; o += (size_t)NSLOT_V * 256;
  float* ss_e = ws + o;    o += 256;
  float* ss_v = ws + o;    o += 256;
  ushort_t* wpack = (ushort_t*)(ws + o);               // 288 frags * 512 ushort
  const ushort_t* Wp_e1 = wpack + (size_t)0 * 512;
  const ushort_t* Wp_e2 = wpack + (size_t)96 * 512;
  const ushort_t* Wp_e3 = wpack + (size_t)128 * 512;
  const ushort_t* Wp_v1 = wpack + (size_t)160 * 512;
  const ushort_t* Wp_v2 = wpack + (size_t)224 * 512;
  const ushort_t* Wp_v3 = wpack + (size_t)256 * 512;

  const size_t zero_bytes =
      ((size_t)NNODES * DV + NNODES + (size_t)NSLOT_E * 256 + (size_t)NSLOT_V * 256) * sizeof(float);
  hipMemsetAsync(d_ws, 0, zero_bytes, stream);

  pack_all<<<72, 256, 0, stream>>>(We1, We2, We3, Wv1, Wv2, Wv3, wpack);

  edge_mlp_mfma<<<NEDGES / 64, 256, 0, stream>>>(node_fea, edge_fea, idx1, idx2,
                                                 Wp_e1, be1, Wp_e2, be2, Wp_e3, be3,
                                                 out_edge, slots_e);
  stats_reduce<<<1, 256, 0, stream>>>(slots_e, NSLOT_E, 1.f / NEDGES, gamma_e, beta_e, ss_e);
  edge_finalize<<<NEDGES / 8, 256, 0, stream>>>(edge_fea, idx1, ss_e, out_edge, accum, cnt);
  node_mlp_mfma<<<(NNODES + 63) / 64, 256, 0, stream>>>(node_fea, accum, cnt,
                                                        Wp_v1, bv1, Wp_v2, bv2, Wp_v3, bv3,
                                                        out_node, slots_v);
  stats_reduce<<<1, 256, 0, stream>>>(slots_v, NSLOT_V, 1.f / NNODES, gamma_v, beta_v, ss_v);
  node_finalize<<<(NNODES * DV) / 1024, 256, 0, stream>>>(node_fea, ss_v, out_node);
}

// Round 3
// 1450.869 us; speedup vs baseline: 2.6143x; 1.4714x over previous
//
#include <hip/hip_runtime.h>
#include <cstddef>

#define BN_EPS 1e-5f
constexpr int NNODES = 50000;
constexpr int NEDGES = 640000;
constexpr int DV = 128;
constexpr int NSLOT_E = 512;
constexpr int NSLOT_V = 256;

typedef __attribute__((ext_vector_type(4))) float f32x4;
typedef __attribute__((ext_vector_type(8))) short s16x8;
typedef unsigned short ushort_t;

__device__ __forceinline__ float lrelu(float x) { return x > 0.f ? x : 0.2f * x; }

__device__ __forceinline__ short f2bf(float f) {
  unsigned int u = __builtin_bit_cast(unsigned int, f);
  u += 0x7fffu + ((u >> 16) & 1u);   // round-to-nearest-even
  return (short)(u >> 16);
}

// ---- weight pre-pack: [K][128] f32 -> per-fragment bf16 layout ----
// frag (kk,n): lane holds B[k = kk*32 + (lane>>4)*8 + j][col = n*16 + (lane&15)], j=0..7
__global__ __launch_bounds__(256)
void pack_all(const float* __restrict__ W0, const float* __restrict__ W1,
              const float* __restrict__ W2, const float* __restrict__ W3,
              const float* __restrict__ W4, const float* __restrict__ W5,
              ushort_t* __restrict__ out) {
  int t = blockIdx.x * 256 + threadIdx.x;
  if (t >= 288 * 64) return;
  int lane = t & 63, f = t >> 6;
  const float* W; int lf;
  if (f < 96)       { W = W0; lf = f; }
  else if (f < 128) { W = W1; lf = f - 96; }
  else if (f < 160) { W = W2; lf = f - 128; }
  else if (f < 224) { W = W3; lf = f - 160; }
  else if (f < 256) { W = W4; lf = f - 224; }
  else              { W = W5; lf = f - 256; }
  int kk = lf >> 3, n = lf & 7;
  int k0 = kk * 32 + (lane >> 4) * 8, col = n * 16 + (lane & 15);
  s16x8 v;
#pragma unroll
  for (int j = 0; j < 8; j++) v[j] = f2bf(W[(size_t)(k0 + j) * DV + col]);
  *(s16x8*)(out + (size_t)t * 8) = v;
}

// ---- CSR build over idx1 ----
__global__ __launch_bounds__(256)
void csr_hist(const int* __restrict__ idx1, int* __restrict__ deg) {
  int e = blockIdx.x * 256 + threadIdx.x;
  if (e < NEDGES) atomicAdd(&deg[idx1[e]], 1);
}

__global__ __launch_bounds__(256)
void csr_scan(const int* __restrict__ deg, int* __restrict__ row_ptr,
              int* __restrict__ cursor) {
  __shared__ int part[256];
  const int t = threadIdx.x;
  const int CH = (NNODES + 255) / 256;
  int s = 0;
  for (int i = 0; i < CH; i++) { int n = t * CH + i; if (n < NNODES) s += deg[n]; }
  part[t] = s;
  __syncthreads();
  if (t == 0) {
    int run = 0;
    for (int i = 0; i < 256; i++) { int v = part[i]; part[i] = run; run += v; }
  }
  __syncthreads();
  int run = part[t];
  for (int i = 0; i < CH; i++) {
    int n = t * CH + i;
    if (n < NNODES) { row_ptr[n] = run; cursor[n] = run; run += deg[n]; }
  }
}

__global__ __launch_bounds__(256)
void csr_fill(const int* __restrict__ idx1, int* __restrict__ cursor,
              int* __restrict__ eidx) {
  int e = blockIdx.x * 256 + threadIdx.x;
  if (e < NEDGES) {
    int pos = atomicAdd(&cursor[idx1[e]], 1);
    eidx[pos] = e;
  }
}

// ---- fused MLP layer: A from swizzled LDS (row stride K*2 B), B frags from global ----
template<int K>
__device__ __forceinline__ void layer_mfma(const char* Als, const s16x8* __restrict__ Wp,
                                           f32x4 acc[8], int lane, int rbase) {
  const int arow = rbase + (lane & 15);
  const int rowoff = arow * (K * 2);
  const int kg16 = (lane >> 4) * 16;
  const int sw = (arow & 7) << 4;
#pragma unroll
  for (int n = 0; n < 8; n++) acc[n] = 0.0f;
#pragma unroll 2
  for (int kk = 0; kk < K / 32; kk++) {
    s16x8 a = *(const s16x8*)(Als + rowoff + ((kk * 64 + kg16) ^ sw));
#pragma unroll
    for (int n = 0; n < 8; n++) {
      s16x8 b = Wp[(kk * 8 + n) * 64 + lane];
      acc[n] = __builtin_amdgcn_mfma_f32_16x16x32_bf16(a, b, acc[n], 0, 0, 0);
    }
  }
}

// bias + lrelu + bf16 -> swizzled LDS (row stride 256B)
__device__ __forceinline__ void store_h_lds(char* H, const f32x4 acc[8],
                                            const float* __restrict__ bias,
                                            int lane, int rbase) {
  const int col0 = lane & 15, rg = lane >> 4;
#pragma unroll
  for (int n = 0; n < 8; n++) {
    float bi = bias[n * 16 + col0];
#pragma unroll
    for (int r = 0; r < 4; r++) {
      int row = rbase + rg * 4 + r;
      float v = lrelu(acc[n][r] + bi);
      *(ushort_t*)(H + row * 256 + ((((n * 16 + col0) * 2)) ^ ((row & 7) << 4))) = (ushort_t)f2bf(v);
    }
  }
}

__global__ __launch_bounds__(256)
void edge_mlp_mfma(const float* __restrict__ node_fea, const float* __restrict__ edge_fea,
                   const int* __restrict__ idx1, const int* __restrict__ idx2,
                   const ushort_t* __restrict__ Wp1, const float* __restrict__ b1,
                   const ushort_t* __restrict__ Wp2, const float* __restrict__ b2,
                   const ushort_t* __restrict__ Wp3, const float* __restrict__ b3,
                   float* __restrict__ h_out, float* __restrict__ slots) {
  __shared__ __align__(16) char zsm[64 * 768];   // z tile (bf16, swizzled), later h2
  __shared__ __align__(16) char hb[64 * 256];    // h1 tile, later BN partials
  const int tid = threadIdx.x;
  const int lane = tid & 63, wid = tid >> 6;
  const int e0 = blockIdx.x * 64;

  for (int t = tid; t < 64 * 48; t += 256) {
    int e = t / 48, p = t % 48;
    int er = e0 + e;
    const float* src;
    if (p < 16)      src = node_fea + (size_t)idx1[er] * DV + p * 8;
    else if (p < 32) src = node_fea + (size_t)idx2[er] * DV + (p - 16) * 8;
    else             src = edge_fea + (size_t)er * DV + (p - 32) * 8;
    float4 x0 = *(const float4*)src;
    float4 x1 = *(const float4*)(src + 4);
    s16x8 v;
    v[0] = f2bf(x0.x); v[1] = f2bf(x0.y); v[2] = f2bf(x0.z); v[3] = f2bf(x0.w);
    v[4] = f2bf(x1.x); v[5] = f2bf(x1.y); v[6] = f2bf(x1.z); v[7] = f2bf(x1.w);
    *(s16x8*)(zsm + e * 768 + ((p * 16) ^ ((e & 7) << 4))) = v;
  }
  __syncthreads();

  const int rbase = wid * 16;
  f32x4 acc[8];

  layer_mfma<384>(zsm, (const s16x8*)Wp1, acc, lane, rbase);
  store_h_lds(hb, acc, b1, lane, rbase);
  __syncthreads();

  layer_mfma<128>(hb, (const s16x8*)Wp2, acc, lane, rbase);
  __syncthreads();
  store_h_lds(zsm, acc, b2, lane, rbase);
  __syncthreads();

  layer_mfma<128>(zsm, (const s16x8*)Wp3, acc, lane, rbase);

  const int col0 = lane & 15, rg = lane >> 4;
  float* ps = (float*)hb;          // [16][128]
  float* pq = ps + 2048;           // [16][128]
#pragma unroll
  for (int n = 0; n < 8; n++) {
    float bi = b3[n * 16 + col0];
    float s = 0.f, q = 0.f;
#pragma unroll
    for (int r = 0; r < 4; r++) {
      int row = rbase + rg * 4 + r;
      float v = acc[n][r] + bi;
      h_out[(size_t)(e0 + row) * DV + n * 16 + col0] = v;
      s += v; q += v * v;
    }
    ps[(wid * 4 + rg) * DV + n * 16 + col0] = s;
    pq[(wid * 4 + rg) * DV + n * 16 + col0] = q;
  }
  __syncthreads();
  if (tid < 128) {
    float s = 0.f, q = 0.f;
#pragma unroll
    for (int g = 0; g < 16; g++) { s += ps[g * DV + tid]; q += pq[g * DV + tid]; }
    float* sl = slots + (size_t)(blockIdx.x % NSLOT_E) * 256;
    atomicAdd(sl + tid, s);
    atomicAdd(sl + 128 + tid, q);
  }
}

// ---- per-node gather of pre-BN h3 rows; writes vi_e_bar with sc/sh folded ----
__global__ __launch_bounds__(256)
void node_gather(const float* __restrict__ h3, const int* __restrict__ row_ptr,
                 const int* __restrict__ deg, const int* __restrict__ eidx,
                 const float* __restrict__ ss, float* __restrict__ vbar) {
  const int n = blockIdx.x * 4 + (threadIdx.x >> 6);
  const int lane = threadIdx.x & 63;
  if (n >= NNODES) return;
  const int start = row_ptr[n], d = deg[n];
  float a0 = 0.f, a1 = 0.f;
  int i = 0;
  for (; i + 2 <= d; i += 2) {
    int e0 = eidx[start + i], e1 = eidx[start + i + 1];
    float2 v0 = *(const float2*)(h3 + (size_t)e0 * DV + lane * 2);
    float2 v1 = *(const float2*)(h3 + (size_t)e1 * DV + lane * 2);
    a0 += v0.x + v1.x; a1 += v0.y + v1.y;
  }
  if (i < d) {
    int e0 = eidx[start + i];
    float2 v0 = *(const float2*)(h3 + (size_t)e0 * DV + lane * 2);
    a0 += v0.x; a1 += v0.y;
  }
  const int j = lane * 2;
  float2 o;
  if (d > 0) {
    float inv = 1.f / (float)d;
    o.x = fmaf(a0 * inv, ss[j], ss[128 + j]);
    o.y = fmaf(a1 * inv, ss[j + 1], ss[128 + j + 1]);
  } else {
    o.x = 0.f; o.y = 0.f;
  }
  *(float2*)(vbar + (size_t)n * DV + j) = o;
}

// ---- streaming edge residual+BN (in place over h3) ----
__global__ __launch_bounds__(256)
void edge_finalize_lite(const float* __restrict__ edge_fea, const float* __restrict__ ss,
                        float* __restrict__ h_inout) {
  const size_t base = (size_t)blockIdx.x * 1024 + threadIdx.x * 4;
  const int j = (int)(base & 127);
  float4 h = *(float4*)&h_inout[base];
  float4 ef = *(const float4*)&edge_fea[base];
  float4 o;
  o.x = ef.x + fmaf(h.x, ss[j + 0], ss[128 + j + 0]);
  o.y = ef.y + fmaf(h.y, ss[j + 1], ss[128 + j + 1]);
  o.z = ef.z + fmaf(h.z, ss[j + 2], ss[128 + j + 2]);
  o.w = ef.w + fmaf(h.w, ss[j + 3], ss[128 + j + 3]);
  *(float4*)&h_inout[base] = o;
}

__global__ __launch_bounds__(256)
void node_mlp_mfma(const float* __restrict__ node_fea, const float* __restrict__ vbar,
                   const ushort_t* __restrict__ Wp1, const float* __restrict__ b1,
                   const ushort_t* __restrict__ Wp2, const float* __restrict__ b2,
                   const ushort_t* __restrict__ Wp3, const float* __restrict__ b3,
                   float* __restrict__ h_out, float* __restrict__ slots) {
  __shared__ __align__(16) char zsm[64 * 512];   // z2 tile (bf16, swizzled), later h2
  __shared__ __align__(16) char hb[64 * 256];
  const int tid = threadIdx.x;
  const int lane = tid & 63, wid = tid >> 6;
  const int n0 = blockIdx.x * 64;

  for (int t = tid; t < 64 * 32; t += 256) {
    int e = t / 32, p = t % 32;
    int nr = n0 + e;
    s16x8 v;
    if (nr < NNODES) {
      const float* src = (p < 16) ? (vbar + (size_t)nr * DV + p * 8)
                                  : (node_fea + (size_t)nr * DV + (p - 16) * 8);
      float4 x0 = *(const float4*)src;
      float4 x1 = *(const float4*)(src + 4);
      v[0] = f2bf(x0.x); v[1] = f2bf(x0.y); v[2] = f2bf(x0.z); v[3] = f2bf(x0.w);
      v[4] = f2bf(x1.x); v[5] = f2bf(x1.y); v[6] = f2bf(x1.z); v[7] = f2bf(x1.w);
    } else {
      v = (s16x8)0;
    }
    *(s16x8*)(zsm + e * 512 + ((p * 16) ^ ((e & 7) << 4))) = v;
  }
  __syncthreads();

  const int rbase = wid * 16;
  f32x4 acc[8];

  layer_mfma<256>(zsm, (const s16x8*)Wp1, acc, lane, rbase);
  store_h_lds(hb, acc, b1, lane, rbase);
  __syncthreads();

  layer_mfma<128>(hb, (const s16x8*)Wp2, acc, lane, rbase);
  __syncthreads();
  store_h_lds(zsm, acc, b2, lane, rbase);
  __syncthreads();

  layer_mfma<128>(zsm, (const s16x8*)Wp3, acc, lane, rbase);

  const int col0 = lane & 15, rg = lane >> 4;
  float* ps = (float*)hb;
  float* pq = ps + 2048;
#pragma unroll
  for (int n = 0; n < 8; n++) {
    float bi = b3[n * 16 + col0];
    float s = 0.f, q = 0.f;
#pragma unroll
    for (int r = 0; r < 4; r++) {
      int row = rbase + rg * 4 + r;
      int gr = n0 + row;
      if (gr < NNODES) {
        float v = acc[n][r] + bi;
        h_out[(size_t)gr * DV + n * 16 + col0] = v;
        s += v; q += v * v;
      }
    }
    ps[(wid * 4 + rg) * DV + n * 16 + col0] = s;
    pq[(wid * 4 + rg) * DV + n * 16 + col0] = q;
  }
  __syncthreads();
  if (tid < 128) {
    float s = 0.f, q = 0.f;
#pragma unroll
    for (int g = 0; g < 16; g++) { s += ps[g * DV + tid]; q += pq[g * DV + tid]; }
    float* sl = slots + (size_t)(blockIdx.x % NSLOT_V) * 256;
    atomicAdd(sl + tid, s);
    atomicAdd(sl + 128 + tid, q);
  }
}

__global__ __launch_bounds__(256)
void stats_reduce(const float* __restrict__ slots, int nslot, float inv_n,
                  const float* __restrict__ gamma, const float* __restrict__ beta,
                  float* __restrict__ ss) {
  __shared__ float tot[256];
  const int j = threadIdx.x;
  float s = 0.f;
  for (int t = 0; t < nslot; t++) s += slots[(size_t)t * 256 + j];
  tot[j] = s;
  __syncthreads();
  if (j < 128) {
    float mean = tot[j] * inv_n;
    float var = tot[j + 128] * inv_n - mean * mean;
    float rs = rsqrtf(var + BN_EPS);
    float sc = gamma[j] * rs;
    ss[j] = sc;
    ss[128 + j] = beta[j] - mean * sc;
  }
}

__global__ __launch_bounds__(256)
void node_finalize(const float* __restrict__ node_fea, const float* __restrict__ ss,
                   float* __restrict__ h_inout) {
  const size_t base = (size_t)blockIdx.x * 1024 + threadIdx.x * 4;
  const int j = (int)(base & 127);
  float4 h = *(float4*)&h_inout[base];
  float4 nf = *(const float4*)&node_fea[base];
  float4 o;
  o.x = nf.x + fmaf(h.x, ss[j + 0], ss[128 + j + 0]);
  o.y = nf.y + fmaf(h.y, ss[j + 1], ss[128 + j + 1]);
  o.z = nf.z + fmaf(h.z, ss[j + 2], ss[128 + j + 2]);
  o.w = nf.w + fmaf(h.w, ss[j + 3], ss[128 + j + 3]);
  *(float4*)&h_inout[base] = o;
}

extern "C" void kernel_launch(void* const* d_in, const int* in_sizes, int n_in,
                              void* d_out, int out_size, void* d_ws, size_t ws_size,
                              hipStream_t stream) {
  const float* node_fea = (const float*)d_in[0];
  const float* edge_fea = (const float*)d_in[1];
  const int* idx1 = (const int*)d_in[2];
  const int* idx2 = (const int*)d_in[3];
  const float* We1 = (const float*)d_in[4];  const float* be1 = (const float*)d_in[5];
  const float* We2 = (const float*)d_in[6];  const float* be2 = (const float*)d_in[7];
  const float* We3 = (const float*)d_in[8];  const float* be3 = (const float*)d_in[9];
  const float* Wv1 = (const float*)d_in[10]; const float* bv1 = (const float*)d_in[11];
  const float* Wv2 = (const float*)d_in[12]; const float* bv2 = (const float*)d_in[13];
  const float* Wv3 = (const float*)d_in[14]; const float* bv3 = (const float*)d_in[15];
  const float* gamma_e = (const float*)d_in[16]; const float* beta_e = (const float*)d_in[17];
  const float* gamma_v = (const float*)d_in[18]; const float* beta_v = (const float*)d_in[19];

  float* out_node = (float*)d_out;                     // [NNODES][128]
  float* out_edge = out_node + (size_t)NNODES * DV;    // [NEDGES][128]

  float* ws = (float*)d_ws;
  size_t o = 0;
  // zeroed region first: deg + BN slots
  int* deg = (int*)(ws + o);      o += NNODES;
  float* slots_e = ws + o;        o += (size_t)NSLOT_E * 256;
  float* slots_v = ws + o;        o += (size_t)NSLOT_V * 256;
  const size_t zero_bytes = o * sizeof(float);
  // non-zeroed scratch
  int* row_ptr = (int*)(ws + o);  o += NNODES;
  int* cursor = (int*)(ws + o);   o += NNODES;
  int* eidx = (int*)(ws + o);     o += NEDGES;
  float* vbar = ws + o;           o += (size_t)NNODES * DV;
  float* ss_e = ws + o;           o += 256;
  float* ss_v = ws + o;           o += 256;
  ushort_t* wpack = (ushort_t*)(ws + o);               // 288 frags * 512 ushort = 288KB

  const ushort_t* Wp_e1 = wpack;
  const ushort_t* Wp_e2 = wpack + (size_t)96 * 512;
  const ushort_t* Wp_e3 = wpack + (size_t)128 * 512;
  const ushort_t* Wp_v1 = wpack + (size_t)160 * 512;
  const ushort_t* Wp_v2 = wpack + (size_t)224 * 512;
  const ushort_t* Wp_v3 = wpack + (size_t)256 * 512;

  hipMemsetAsync(d_ws, 0, zero_bytes, stream);

  pack_all<<<72, 256, 0, stream>>>(We1, We2, We3, Wv1, Wv2, Wv3, wpack);
  csr_hist<<<(NEDGES + 255) / 256, 256, 0, stream>>>(idx1, deg);
  csr_scan<<<1, 256, 0, stream>>>(deg, row_ptr, cursor);
  csr_fill<<<(NEDGES + 255) / 256, 256, 0, stream>>>(idx1, cursor, eidx);

  edge_mlp_mfma<<<NEDGES / 64, 256, 0, stream>>>(node_fea, edge_fea, idx1, idx2,
                                                 Wp_e1, be1, Wp_e2, be2, Wp_e3, be3,
                                                 out_edge, slots_e);
  stats_reduce<<<1, 256, 0, stream>>>(slots_e, NSLOT_E, 1.f / NEDGES, gamma_e, beta_e, ss_e);
  node_gather<<<(NNODES + 3) / 4, 256, 0, stream>>>(out_edge, row_ptr, deg, eidx, ss_e, vbar);
  edge_finalize_lite<<<(NEDGES * DV) / 1024, 256, 0, stream>>>(edge_fea, ss_e, out_edge);
  node_mlp_mfma<<<(NNODES + 63) / 64, 256, 0, stream>>>(node_fea, vbar,
                                                        Wp_v1, bv1, Wp_v2, bv2, Wp_v3, bv3,
                                                        out_node, slots_v);
  stats_reduce<<<1, 256, 0, stream>>>(slots_v, NSLOT_V, 1.f / NNODES, gamma_v, beta_v, ss_v);
  node_finalize<<<(NNODES * DV) / 1024, 256, 0, stream>>>(node_fea, ss_v, out_node);
}

// Round 4
// 1166.279 us; speedup vs baseline: 3.2523x; 1.2440x over previous
//
#include <hip/hip_runtime.h>
#include <cstddef>

#define BN_EPS 1e-5f
constexpr int NNODES = 50000;
constexpr int NEDGES = 640000;
constexpr int DV = 128;
constexpr int NSLOT_E = 512;
constexpr int NSLOT_V = 256;

typedef __attribute__((ext_vector_type(4))) float f32x4;
typedef __attribute__((ext_vector_type(8))) short s16x8;
typedef unsigned short ushort_t;

__device__ __forceinline__ float lrelu(float x) { return x > 0.f ? x : 0.2f * x; }

__device__ __forceinline__ short f2bf(float f) {
  unsigned int u = __builtin_bit_cast(unsigned int, f);
  u += 0x7fffu + ((u >> 16) & 1u);   // round-to-nearest-even
  return (short)(u >> 16);
}

// ---- weight pre-pack: [K][128] f32 -> per-fragment bf16 layout ----
// frag (kk,n): lane holds B[k = kk*32 + (lane>>4)*8 + j][col = n*16 + (lane&15)], j=0..7
__global__ __launch_bounds__(256)
void pack_all(const float* __restrict__ W0, const float* __restrict__ W1,
              const float* __restrict__ W2, const float* __restrict__ W3,
              const float* __restrict__ W4, const float* __restrict__ W5,
              ushort_t* __restrict__ out) {
  int t = blockIdx.x * 256 + threadIdx.x;
  if (t >= 288 * 64) return;
  int lane = t & 63, f = t >> 6;
  const float* W; int lf;
  if (f < 96)       { W = W0; lf = f; }
  else if (f < 128) { W = W1; lf = f - 96; }
  else if (f < 160) { W = W2; lf = f - 128; }
  else if (f < 224) { W = W3; lf = f - 160; }
  else if (f < 256) { W = W4; lf = f - 224; }
  else              { W = W5; lf = f - 256; }
  int kk = lf >> 3, n = lf & 7;
  int k0 = kk * 32 + (lane >> 4) * 8, col = n * 16 + (lane & 15);
  s16x8 v;
#pragma unroll
  for (int j = 0; j < 8; j++) v[j] = f2bf(W[(size_t)(k0 + j) * DV + col]);
  *(s16x8*)(out + (size_t)t * 8) = v;
}

// ---- CSR build over idx1 ----
__global__ __launch_bounds__(256)
void csr_hist(const int* __restrict__ idx1, int* __restrict__ deg) {
  int e = blockIdx.x * 256 + threadIdx.x;
  if (e < NEDGES) atomicAdd(&deg[idx1[e]], 1);
}

__global__ __launch_bounds__(256)
void csr_scan(const int* __restrict__ deg, int* __restrict__ row_ptr,
              int* __restrict__ cursor) {
  __shared__ int part[256];
  const int t = threadIdx.x;
  const int CH = (NNODES + 255) / 256;
  int s = 0;
  for (int i = 0; i < CH; i++) { int n = t * CH + i; if (n < NNODES) s += deg[n]; }
  part[t] = s;
  __syncthreads();
  if (t == 0) {
    int run = 0;
    for (int i = 0; i < 256; i++) { int v = part[i]; part[i] = run; run += v; }
  }
  __syncthreads();
  int run = part[t];
  for (int i = 0; i < CH; i++) {
    int n = t * CH + i;
    if (n < NNODES) { row_ptr[n] = run; cursor[n] = run; run += deg[n]; }
  }
}

__global__ __launch_bounds__(256)
void csr_fill(const int* __restrict__ idx1, int* __restrict__ cursor,
              int* __restrict__ eidx) {
  int e = blockIdx.x * 256 + threadIdx.x;
  if (e < NEDGES) {
    int pos = atomicAdd(&cursor[idx1[e]], 1);
    eidx[pos] = e;
  }
}

// ---- fused MLP layer: wave covers 16 rows (rg) x 64 cols (nh) of a 32-row tile.
// A from swizzled LDS (row stride K*2 B), B frags (4 of 8 n's) from global.
template<int K>
__device__ __forceinline__ void layer_mfma(const char* Als, const s16x8* __restrict__ Wp,
                                           f32x4 acc[4], int lane, int rg, int nh) {
  const int arow = rg * 16 + (lane & 15);
  const int rowoff = arow * (K * 2);
  const int kg16 = (lane >> 4) * 16;
  const int sw = (arow & 7) << 4;
#pragma unroll
  for (int n = 0; n < 4; n++) acc[n] = 0.0f;
#pragma unroll 2
  for (int kk = 0; kk < K / 32; kk++) {
    s16x8 a = *(const s16x8*)(Als + rowoff + ((kk * 64 + kg16) ^ sw));
#pragma unroll
    for (int n = 0; n < 4; n++) {
      s16x8 b = Wp[(size_t)(kk * 8 + nh * 4 + n) * 64 + lane];
      acc[n] = __builtin_amdgcn_mfma_f32_16x16x32_bf16(a, b, acc[n], 0, 0, 0);
    }
  }
}

// bias + lrelu + bf16 -> swizzled LDS (row stride 256B)
__device__ __forceinline__ void store_h_lds(char* H, const f32x4 acc[4],
                                            const float* __restrict__ bias,
                                            int lane, int rg, int nh) {
  const int col0 = lane & 15, lg = lane >> 4;
#pragma unroll
  for (int n = 0; n < 4; n++) {
    const int col = nh * 64 + n * 16 + col0;
    float bi = bias[col];
#pragma unroll
    for (int r = 0; r < 4; r++) {
      int row = rg * 16 + lg * 4 + r;
      float v = lrelu(acc[n][r] + bi);
      *(ushort_t*)(H + row * 256 + ((col * 2) ^ ((row & 7) << 4))) = (ushort_t)f2bf(v);
    }
  }
}

__global__ __launch_bounds__(256)
void edge_mlp_mfma(const float* __restrict__ node_fea, const float* __restrict__ edge_fea,
                   const int* __restrict__ idx1, const int* __restrict__ idx2,
                   const ushort_t* __restrict__ Wp1, const float* __restrict__ b1,
                   const ushort_t* __restrict__ Wp2, const float* __restrict__ b2,
                   const ushort_t* __restrict__ Wp3, const float* __restrict__ b3,
                   float* __restrict__ h_out, float* __restrict__ slots) {
  __shared__ __align__(16) char zsm[32 * 768];   // 24KB: z tile, later h2 + BN pq
  __shared__ __align__(16) char hb[32 * 256];    // 8KB: h1 tile, later BN ps
  const int tid = threadIdx.x;
  const int lane = tid & 63, wid = tid >> 6;
  const int rg = wid & 1, nh = wid >> 1;
  const int e0 = blockIdx.x * 32;

  // gather z = [node[idx1] | node[idx2] | edge] as bf16 into swizzled LDS
  for (int t = tid; t < 32 * 48; t += 256) {
    int e = t / 48, p = t % 48;
    int er = e0 + e;
    const float* src;
    if (p < 16)      src = node_fea + (size_t)idx1[er] * DV + p * 8;
    else if (p < 32) src = node_fea + (size_t)idx2[er] * DV + (p - 16) * 8;
    else             src = edge_fea + (size_t)er * DV + (p - 32) * 8;
    float4 x0 = *(const float4*)src;
    float4 x1 = *(const float4*)(src + 4);
    s16x8 v;
    v[0] = f2bf(x0.x); v[1] = f2bf(x0.y); v[2] = f2bf(x0.z); v[3] = f2bf(x0.w);
    v[4] = f2bf(x1.x); v[5] = f2bf(x1.y); v[6] = f2bf(x1.z); v[7] = f2bf(x1.w);
    *(s16x8*)(zsm + e * 768 + ((p * 16) ^ ((e & 7) << 4))) = v;
  }
  __syncthreads();

  f32x4 acc[4];

  layer_mfma<384>(zsm, (const s16x8*)Wp1, acc, lane, rg, nh);
  store_h_lds(hb, acc, b1, lane, rg, nh);
  __syncthreads();

  layer_mfma<128>(hb, (const s16x8*)Wp2, acc, lane, rg, nh);
  __syncthreads();                 // all zsm reads done
  store_h_lds(zsm, acc, b2, lane, rg, nh);
  __syncthreads();

  layer_mfma<128>(zsm, (const s16x8*)Wp3, acc, lane, rg, nh);

  // epilogue: bias, store pre-BN h3 (f32) to global, BN partials
  const int col0 = lane & 15, lg = lane >> 4;
  float* ps = (float*)hb;                 // [8][128] 4KB
  float* pq = (float*)(zsm);              // [8][128] 4KB
#pragma unroll
  for (int n = 0; n < 4; n++) {
    const int col = nh * 64 + n * 16 + col0;
    float bi = b3[col];
    float s = 0.f, q = 0.f;
#pragma unroll
    for (int r = 0; r < 4; r++) {
      int row = rg * 16 + lg * 4 + r;
      float v = acc[n][r] + bi;
      h_out[(size_t)(e0 + row) * DV + col] = v;
      s += v; q += v * v;
    }
    ps[(rg * 4 + lg) * DV + col] = s;
    pq[(rg * 4 + lg) * DV + col] = q;
  }
  __syncthreads();
  if (tid < 128) {
    float s = 0.f, q = 0.f;
#pragma unroll
    for (int g = 0; g < 8; g++) { s += ps[g * DV + tid]; q += pq[g * DV + tid]; }
    float* sl = slots + (size_t)(blockIdx.x % NSLOT_E) * 256;
    atomicAdd(sl + tid, s);
    atomicAdd(sl + 128 + tid, q);
  }
}

// ---- per-node gather of pre-BN h3 rows; writes vi_e_bar with sc/sh folded ----
__global__ __launch_bounds__(256)
void node_gather(const float* __restrict__ h3, const int* __restrict__ row_ptr,
                 const int* __restrict__ deg, const int* __restrict__ eidx,
                 const float* __restrict__ ss, float* __restrict__ vbar) {
  const int n = blockIdx.x * 4 + (threadIdx.x >> 6);
  const int lane = threadIdx.x & 63;
  if (n >= NNODES) return;
  const int start = row_ptr[n], d = deg[n];
  float a0 = 0.f, a1 = 0.f;
  int i = 0;
  for (; i + 4 <= d; i += 4) {
    int e0 = eidx[start + i], e1 = eidx[start + i + 1];
    int e2 = eidx[start + i + 2], e3 = eidx[start + i + 3];
    float2 v0 = *(const float2*)(h3 + (size_t)e0 * DV + lane * 2);
    float2 v1 = *(const float2*)(h3 + (size_t)e1 * DV + lane * 2);
    float2 v2 = *(const float2*)(h3 + (size_t)e2 * DV + lane * 2);
    float2 v3 = *(const float2*)(h3 + (size_t)e3 * DV + lane * 2);
    a0 += (v0.x + v1.x) + (v2.x + v3.x);
    a1 += (v0.y + v1.y) + (v2.y + v3.y);
  }
  for (; i < d; i++) {
    int e0 = eidx[start + i];
    float2 v0 = *(const float2*)(h3 + (size_t)e0 * DV + lane * 2);
    a0 += v0.x; a1 += v0.y;
  }
  const int j = lane * 2;
  float2 o;
  if (d > 0) {
    float inv = 1.f / (float)d;
    o.x = fmaf(a0 * inv, ss[j], ss[128 + j]);
    o.y = fmaf(a1 * inv, ss[j + 1], ss[128 + j + 1]);
  } else {
    o.x = 0.f; o.y = 0.f;
  }
  *(float2*)(vbar + (size_t)n * DV + j) = o;
}

// ---- streaming edge residual+BN (in place over h3) ----
__global__ __launch_bounds__(256)
void edge_finalize_lite(const float* __restrict__ edge_fea, const float* __restrict__ ss,
                        float* __restrict__ h_inout) {
  const size_t base = (size_t)blockIdx.x * 1024 + threadIdx.x * 4;
  const int j = (int)(base & 127);
  float4 h = *(float4*)&h_inout[base];
  float4 ef = *(const float4*)&edge_fea[base];
  float4 o;
  o.x = ef.x + fmaf(h.x, ss[j + 0], ss[128 + j + 0]);
  o.y = ef.y + fmaf(h.y, ss[j + 1], ss[128 + j + 1]);
  o.z = ef.z + fmaf(h.z, ss[j + 2], ss[128 + j + 2]);
  o.w = ef.w + fmaf(h.w, ss[j + 3], ss[128 + j + 3]);
  *(float4*)&h_inout[base] = o;
}

__global__ __launch_bounds__(256)
void node_mlp_mfma(const float* __restrict__ node_fea, const float* __restrict__ vbar,
                   const ushort_t* __restrict__ Wp1, const float* __restrict__ b1,
                   const ushort_t* __restrict__ Wp2, const float* __restrict__ b2,
                   const ushort_t* __restrict__ Wp3, const float* __restrict__ b3,
                   float* __restrict__ h_out, float* __restrict__ slots) {
  __shared__ __align__(16) char zsm[32 * 512];   // 16KB
  __shared__ __align__(16) char hb[32 * 256];    // 8KB
  const int tid = threadIdx.x;
  const int lane = tid & 63, wid = tid >> 6;
  const int rg = wid & 1, nh = wid >> 1;
  const int n0 = blockIdx.x * 32;

  for (int t = tid; t < 32 * 32; t += 256) {
    int e = t / 32, p = t % 32;
    int nr = n0 + e;
    s16x8 v;
    if (nr < NNODES) {
      const float* src = (p < 16) ? (vbar + (size_t)nr * DV + p * 8)
                                  : (node_fea + (size_t)nr * DV + (p - 16) * 8);
      float4 x0 = *(const float4*)src;
      float4 x1 = *(const float4*)(src + 4);
      v[0] = f2bf(x0.x); v[1] = f2bf(x0.y); v[2] = f2bf(x0.z); v[3] = f2bf(x0.w);
      v[4] = f2bf(x1.x); v[5] = f2bf(x1.y); v[6] = f2bf(x1.z); v[7] = f2bf(x1.w);
    } else {
      v = (s16x8)0;
    }
    *(s16x8*)(zsm + e * 512 + ((p * 16) ^ ((e & 7) << 4))) = v;
  }
  __syncthreads();

  f32x4 acc[4];

  layer_mfma<256>(zsm, (const s16x8*)Wp1, acc, lane, rg, nh);
  store_h_lds(hb, acc, b1, lane, rg, nh);
  __syncthreads();

  layer_mfma<128>(hb, (const s16x8*)Wp2, acc, lane, rg, nh);
  __syncthreads();
  store_h_lds(zsm, acc, b2, lane, rg, nh);
  __syncthreads();

  layer_mfma<128>(zsm, (const s16x8*)Wp3, acc, lane, rg, nh);

  const int col0 = lane & 15, lg = lane >> 4;
  float* ps = (float*)hb;
  float* pq = (float*)zsm;
#pragma unroll
  for (int n = 0; n < 4; n++) {
    const int col = nh * 64 + n * 16 + col0;
    float bi = b3[col];
    float s = 0.f, q = 0.f;
#pragma unroll
    for (int r = 0; r < 4; r++) {
      int row = rg * 16 + lg * 4 + r;
      int gr = n0 + row;
      if (gr < NNODES) {
        float v = acc[n][r] + bi;
        h_out[(size_t)gr * DV + col] = v;
        s += v; q += v * v;
      }
    }
    ps[(rg * 4 + lg) * DV + col] = s;
    pq[(rg * 4 + lg) * DV + col] = q;
  }
  __syncthreads();
  if (tid < 128) {
    float s = 0.f, q = 0.f;
#pragma unroll
    for (int g = 0; g < 8; g++) { s += ps[g * DV + tid]; q += pq[g * DV + tid]; }
    float* sl = slots + (size_t)(blockIdx.x % NSLOT_V) * 256;
    atomicAdd(sl + tid, s);
    atomicAdd(sl + 128 + tid, q);
  }
}

__global__ __launch_bounds__(256)
void stats_reduce(const float* __restrict__ slots, int nslot, float inv_n,
                  const float* __restrict__ gamma, const float* __restrict__ beta,
                  float* __restrict__ ss) {
  __shared__ float tot[256];
  const int j = threadIdx.x;
  float s = 0.f;
  for (int t = 0; t < nslot; t++) s += slots[(size_t)t * 256 + j];
  tot[j] = s;
  __syncthreads();
  if (j < 128) {
    float mean = tot[j] * inv_n;
    float var = tot[j + 128] * inv_n - mean * mean;
    float rs = rsqrtf(var + BN_EPS);
    float sc = gamma[j] * rs;
    ss[j] = sc;
    ss[128 + j] = beta[j] - mean * sc;
  }
}

__global__ __launch_bounds__(256)
void node_finalize(const float* __restrict__ node_fea, const float* __restrict__ ss,
                   float* __restrict__ h_inout) {
  const size_t base = (size_t)blockIdx.x * 1024 + threadIdx.x * 4;
  const int j = (int)(base & 127);
  float4 h = *(float4*)&h_inout[base];
  float4 nf = *(const float4*)&node_fea[base];
  float4 o;
  o.x = nf.x + fmaf(h.x, ss[j + 0], ss[128 + j + 0]);
  o.y = nf.y + fmaf(h.y, ss[j + 1], ss[128 + j + 1]);
  o.z = nf.z + fmaf(h.z, ss[j + 2], ss[128 + j + 2]);
  o.w = nf.w + fmaf(h.w, ss[j + 3], ss[128 + j + 3]);
  *(float4*)&h_inout[base] = o;
}

extern "C" void kernel_launch(void* const* d_in, const int* in_sizes, int n_in,
                              void* d_out, int out_size, void* d_ws, size_t ws_size,
                              hipStream_t stream) {
  const float* node_fea = (const float*)d_in[0];
  const float* edge_fea = (const float*)d_in[1];
  const int* idx1 = (const int*)d_in[2];
  const int* idx2 = (const int*)d_in[3];
  const float* We1 = (const float*)d_in[4];  const float* be1 = (const float*)d_in[5];
  const float* We2 = (const float*)d_in[6];  const float* be2 = (const float*)d_in[7];
  const float* We3 = (const float*)d_in[8];  const float* be3 = (const float*)d_in[9];
  const float* Wv1 = (const float*)d_in[10]; const float* bv1 = (const float*)d_in[11];
  const float* Wv2 = (const float*)d_in[12]; const float* bv2 = (const float*)d_in[13];
  const float* Wv3 = (const float*)d_in[14]; const float* bv3 = (const float*)d_in[15];
  const float* gamma_e = (const float*)d_in[16]; const float* beta_e = (const float*)d_in[17];
  const float* gamma_v = (const float*)d_in[18]; const float* beta_v = (const float*)d_in[19];

  float* out_node = (float*)d_out;                     // [NNODES][128]
  float* out_edge = out_node + (size_t)NNODES * DV;    // [NEDGES][128]

  float* ws = (float*)d_ws;
  size_t o = 0;
  // zeroed region first: deg + BN slots
  int* deg = (int*)(ws + o);      o += NNODES;
  float* slots_e = ws + o;        o += (size_t)NSLOT_E * 256;
  float* slots_v = ws + o;        o += (size_t)NSLOT_V * 256;
  const size_t zero_bytes = o * sizeof(float);
  // non-zeroed scratch
  int* row_ptr = (int*)(ws + o);  o += NNODES;
  int* cursor = (int*)(ws + o);   o += NNODES;
  int* eidx = (int*)(ws + o);     o += NEDGES;
  float* vbar = ws + o;           o += (size_t)NNODES * DV;
  float* ss_e = ws + o;           o += 256;
  float* ss_v = ws + o;           o += 256;
  ushort_t* wpack = (ushort_t*)(ws + o);               // 288 frags * 512 ushort = 288KB

  const ushort_t* Wp_e1 = wpack;
  const ushort_t* Wp_e2 = wpack + (size_t)96 * 512;
  const ushort_t* Wp_e3 = wpack + (size_t)128 * 512;
  const ushort_t* Wp_v1 = wpack + (size_t)160 * 512;
  const ushort_t* Wp_v2 = wpack + (size_t)224 * 512;
  const ushort_t* Wp_v3 = wpack + (size_t)256 * 512;

  hipMemsetAsync(d_ws, 0, zero_bytes, stream);

  pack_all<<<72, 256, 0, stream>>>(We1, We2, We3, Wv1, Wv2, Wv3, wpack);
  csr_hist<<<(NEDGES + 255) / 256, 256, 0, stream>>>(idx1, deg);
  csr_scan<<<1, 256, 0, stream>>>(deg, row_ptr, cursor);
  csr_fill<<<(NEDGES + 255) / 256, 256, 0, stream>>>(idx1, cursor, eidx);

  edge_mlp_mfma<<<NEDGES / 32, 256, 0, stream>>>(node_fea, edge_fea, idx1, idx2,
                                                 Wp_e1, be1, Wp_e2, be2, Wp_e3, be3,
                                                 out_edge, slots_e);
  stats_reduce<<<1, 256, 0, stream>>>(slots_e, NSLOT_E, 1.f / NEDGES, gamma_e, beta_e, ss_e);
  node_gather<<<(NNODES + 3) / 4, 256, 0, stream>>>(out_edge, row_ptr, deg, eidx, ss_e, vbar);
  edge_finalize_lite<<<(NEDGES * DV) / 1024, 256, 0, stream>>>(edge_fea, ss_e, out_edge);
  node_mlp_mfma<<<(NNODES + 31) / 32, 256, 0, stream>>>(node_fea, vbar,
                                                        Wp_v1, bv1, Wp_v2, bv2, Wp_v3, bv3,
                                                        out_node, slots_v);
  stats_reduce<<<1, 256, 0, stream>>>(slots_v, NSLOT_V, 1.f / NNODES, gamma_v, beta_v, ss_v);
  node_finalize<<<(NNODES * DV) / 1024, 256, 0, stream>>>(node_fea, ss_v, out_node);
}

// Round 5
// 938.081 us; speedup vs baseline: 4.0434x; 1.2433x over previous
//
#include <hip/hip_runtime.h>
#include <cstddef>

#define BN_EPS 1e-5f
constexpr int NNODES = 50000;
constexpr int NEDGES = 640000;
constexpr int DV = 128;
constexpr int NSLOT_E = 512;
constexpr int NSLOT_V = 256;

typedef __attribute__((ext_vector_type(4))) float f32x4;
typedef __attribute__((ext_vector_type(8))) short s16x8;
typedef unsigned short ushort_t;

__device__ __forceinline__ float lrelu(float x) { return x > 0.f ? x : 0.2f * x; }

__device__ __forceinline__ short f2bf(float f) {
  unsigned int u = __builtin_bit_cast(unsigned int, f);
  u += 0x7fffu + ((u >> 16) & 1u);   // round-to-nearest-even
  return (short)(u >> 16);
}

// ---- weight pre-pack: [K][128] f32 -> per-fragment bf16 layout ----
// frag (kk,n): lane holds B[k = kk*32 + (lane>>4)*8 + j][col = n*16 + (lane&15)], j=0..7
__global__ __launch_bounds__(256)
void pack_all(const float* __restrict__ W0, const float* __restrict__ W1,
              const float* __restrict__ W2, const float* __restrict__ W3,
              const float* __restrict__ W4, const float* __restrict__ W5,
              ushort_t* __restrict__ out) {
  int t = blockIdx.x * 256 + threadIdx.x;
  if (t >= 288 * 64) return;
  int lane = t & 63, f = t >> 6;
  const float* W; int lf;
  if (f < 96)       { W = W0; lf = f; }
  else if (f < 128) { W = W1; lf = f - 96; }
  else if (f < 160) { W = W2; lf = f - 128; }
  else if (f < 224) { W = W3; lf = f - 160; }
  else if (f < 256) { W = W4; lf = f - 224; }
  else              { W = W5; lf = f - 256; }
  int kk = lf >> 3, n = lf & 7;
  int k0 = kk * 32 + (lane >> 4) * 8, col = n * 16 + (lane & 15);
  s16x8 v;
#pragma unroll
  for (int j = 0; j < 8; j++) v[j] = f2bf(W[(size_t)(k0 + j) * DV + col]);
  *(s16x8*)(out + (size_t)t * 8) = v;
}

// ---- CSR build over idx1 ----
__global__ __launch_bounds__(256)
void csr_hist(const int* __restrict__ idx1, int* __restrict__ deg) {
  int e = blockIdx.x * 256 + threadIdx.x;
  if (e < NEDGES) atomicAdd(&deg[idx1[e]], 1);
}

__global__ __launch_bounds__(256)
void csr_scan(const int* __restrict__ deg, int* __restrict__ row_ptr,
              int* __restrict__ cursor) {
  __shared__ int part[256];
  const int t = threadIdx.x;
  const int CH = (NNODES + 255) / 256;
  int s = 0;
  for (int i = 0; i < CH; i++) { int n = t * CH + i; if (n < NNODES) s += deg[n]; }
  part[t] = s;
  __syncthreads();
  if (t == 0) {
    int run = 0;
    for (int i = 0; i < 256; i++) { int v = part[i]; part[i] = run; run += v; }
  }
  __syncthreads();
  int run = part[t];
  for (int i = 0; i < CH; i++) {
    int n = t * CH + i;
    if (n < NNODES) { row_ptr[n] = run; cursor[n] = run; run += deg[n]; }
  }
}

__global__ __launch_bounds__(256)
void csr_fill(const int* __restrict__ idx1, int* __restrict__ cursor,
              int* __restrict__ eidx) {
  int e = blockIdx.x * 256 + threadIdx.x;
  if (e < NEDGES) {
    int pos = atomicAdd(&cursor[idx1[e]], 1);
    eidx[pos] = e;
  }
}

// ---- MFMA span: wave covers 32 rows (rg half) x 32 cols (nh quarter) of 64-row tile.
// Per kk: 2 A ds_reads + 2 B frag loads + 4 MFMAs accumulating into acc[2][2].
template<int RS>  // LDS row stride in bytes
__device__ __forceinline__ void mfma_span(const char* Als, const s16x8* __restrict__ Wp,
                                          int fkk0, int nkk, f32x4 acc[2][2],
                                          int lane, int rg, int nh) {
  const int col0 = lane & 15;
  const int kg16 = (lane >> 4) * 16;
  const int sw = (col0 & 7) << 4;
  const int r0 = (rg * 32 + col0) * RS;
  const int r1 = (rg * 32 + 16 + col0) * RS;
#pragma unroll
  for (int kk = 0; kk < nkk; kk++) {
    const int ko = (kk * 64 + kg16) ^ sw;
    s16x8 a0 = *(const s16x8*)(Als + r0 + ko);
    s16x8 a1 = *(const s16x8*)(Als + r1 + ko);
    s16x8 b0 = Wp[(size_t)((fkk0 + kk) * 8 + nh * 2 + 0) * 64 + lane];
    s16x8 b1 = Wp[(size_t)((fkk0 + kk) * 8 + nh * 2 + 1) * 64 + lane];
    acc[0][0] = __builtin_amdgcn_mfma_f32_16x16x32_bf16(a0, b0, acc[0][0], 0, 0, 0);
    acc[0][1] = __builtin_amdgcn_mfma_f32_16x16x32_bf16(a0, b1, acc[0][1], 0, 0, 0);
    acc[1][0] = __builtin_amdgcn_mfma_f32_16x16x32_bf16(a1, b0, acc[1][0], 0, 0, 0);
    acc[1][1] = __builtin_amdgcn_mfma_f32_16x16x32_bf16(a1, b1, acc[1][1], 0, 0, 0);
  }
}

// bias + lrelu + bf16 -> swizzled LDS (row stride 256B), 64-row tile shape
__device__ __forceinline__ void store_h64(char* H, const f32x4 acc[2][2],
                                          const float* __restrict__ bias,
                                          int lane, int rg, int nh) {
  const int col0 = lane & 15, lg = lane >> 4;
#pragma unroll
  for (int ar = 0; ar < 2; ar++) {
#pragma unroll
    for (int n = 0; n < 2; n++) {
      const int col = nh * 32 + n * 16 + col0;
      float bi = bias[col];
#pragma unroll
      for (int r = 0; r < 4; r++) {
        int row = rg * 32 + ar * 16 + lg * 4 + r;
        float v = lrelu(acc[ar][n][r] + bi);
        *(ushort_t*)(H + row * 256 + ((col * 2) ^ ((row & 7) << 4))) = (ushort_t)f2bf(v);
      }
    }
  }
}

__global__ __launch_bounds__(512, 6)
void edge_mlp_mfma(const float* __restrict__ node_fea, const float* __restrict__ edge_fea,
                   const int* __restrict__ idx1, const int* __restrict__ idx2,
                   const ushort_t* __restrict__ Wp1, const float* __restrict__ b1,
                   const ushort_t* __restrict__ Wp2, const float* __restrict__ b2,
                   const ushort_t* __restrict__ Wp3, const float* __restrict__ b3,
                   float* __restrict__ h_out, float* __restrict__ slots) {
  __shared__ __align__(16) char zsm[64 * 384];   // 24KB: z K-half, later h2
  __shared__ __align__(16) char hb[64 * 256];    // 16KB: h1, later BN partials
  const int tid = threadIdx.x;
  const int lane = tid & 63, wid = tid >> 6;
  const int rg = wid & 1, nh = wid >> 1;
  const int e0 = blockIdx.x * 64;

  // ---- gather K-half A: z[:,0:192] = [node1[0:128] | node2[0:64]] as bf16, swizzled
  for (int t = tid; t < 64 * 24; t += 512) {
    int e = t / 24, p = t % 24;
    int er = e0 + e;
    const float* src = (p < 16) ? (node_fea + (size_t)idx1[er] * DV + p * 8)
                                : (node_fea + (size_t)idx2[er] * DV + (p - 16) * 8);
    float4 x0 = *(const float4*)src;
    float4 x1 = *(const float4*)(src + 4);
    s16x8 v;
    v[0] = f2bf(x0.x); v[1] = f2bf(x0.y); v[2] = f2bf(x0.z); v[3] = f2bf(x0.w);
    v[4] = f2bf(x1.x); v[5] = f2bf(x1.y); v[6] = f2bf(x1.z); v[7] = f2bf(x1.w);
    *(s16x8*)(zsm + e * 384 + ((p * 16) ^ ((e & 7) << 4))) = v;
  }
  __syncthreads();

  f32x4 acc[2][2];
#pragma unroll
  for (int i = 0; i < 2; i++)
#pragma unroll
    for (int j = 0; j < 2; j++) acc[i][j] = 0.0f;

  // ---- layer 1, k = 0..191
  mfma_span<384>(zsm, (const s16x8*)Wp1, 0, 6, acc, lane, rg, nh);
  __syncthreads();   // all zsm reads done before overwrite

  // ---- gather K-half B: z[:,192:384] = [node2[64:128] | edge[0:128]]
  for (int t = tid; t < 64 * 24; t += 512) {
    int e = t / 24, p = t % 24;
    int er = e0 + e;
    const float* src = (p < 8) ? (node_fea + (size_t)idx2[er] * DV + 64 + p * 8)
                               : (edge_fea + (size_t)er * DV + (p - 8) * 8);
    float4 x0 = *(const float4*)src;
    float4 x1 = *(const float4*)(src + 4);
    s16x8 v;
    v[0] = f2bf(x0.x); v[1] = f2bf(x0.y); v[2] = f2bf(x0.z); v[3] = f2bf(x0.w);
    v[4] = f2bf(x1.x); v[5] = f2bf(x1.y); v[6] = f2bf(x1.z); v[7] = f2bf(x1.w);
    *(s16x8*)(zsm + e * 384 + ((p * 16) ^ ((e & 7) << 4))) = v;
  }
  __syncthreads();

  // ---- layer 1, k = 192..383 (frags 6..11)
  mfma_span<384>(zsm, (const s16x8*)Wp1, 6, 6, acc, lane, rg, nh);

  store_h64(hb, acc, b1, lane, rg, nh);
  __syncthreads();   // also guarantees all L1b zsm reads finished

  // ---- layer 2 (reads hb)
#pragma unroll
  for (int i = 0; i < 2; i++)
#pragma unroll
    for (int j = 0; j < 2; j++) acc[i][j] = 0.0f;
  mfma_span<256>(hb, (const s16x8*)Wp2, 0, 4, acc, lane, rg, nh);

  store_h64(zsm, acc, b2, lane, rg, nh);   // zsm free (L1b done by all)
  __syncthreads();

  // ---- layer 3 (reads zsm)
#pragma unroll
  for (int i = 0; i < 2; i++)
#pragma unroll
    for (int j = 0; j < 2; j++) acc[i][j] = 0.0f;
  mfma_span<256>(zsm, (const s16x8*)Wp3, 0, 4, acc, lane, rg, nh);

  // ---- epilogue: bias, store pre-BN h3 (f32) to global, BN partials
  const int col0 = lane & 15, lg = lane >> 4;
  float* ps = (float*)hb;            // [16][128] 8KB (hb free after sync above)
  float* pq = ps + 16 * DV;          // [16][128] 8KB
  const int pg = rg * 8 + (lane >> 4) + 0;  // base; +ar*4 below
#pragma unroll
  for (int ar = 0; ar < 2; ar++) {
#pragma unroll
    for (int n = 0; n < 2; n++) {
      const int col = nh * 32 + n * 16 + col0;
      float bi = b3[col];
      float s = 0.f, q = 0.f;
#pragma unroll
      for (int r = 0; r < 4; r++) {
        int row = rg * 32 + ar * 16 + lg * 4 + r;
        float v = acc[ar][n][r] + bi;
        h_out[(size_t)(e0 + row) * DV + col] = v;
        s += v; q += v * v;
      }
      ps[(rg * 8 + ar * 4 + lg) * DV + col] = s;
      pq[(rg * 8 + ar * 4 + lg) * DV + col] = q;
    }
  }
  (void)pg;
  __syncthreads();
  if (tid < 128) {
    float s = 0.f, q = 0.f;
#pragma unroll
    for (int g = 0; g < 16; g++) { s += ps[g * DV + tid]; q += pq[g * DV + tid]; }
    float* sl = slots + (size_t)(blockIdx.x % NSLOT_E) * 256;
    atomicAdd(sl + tid, s);
    atomicAdd(sl + 128 + tid, q);
  }
}

// ---- per-node gather of pre-BN h3 rows; writes vbar AND finalizes out_edge in place ----
__global__ __launch_bounds__(256)
void node_gather_fused(const float* __restrict__ edge_fea, const int* __restrict__ row_ptr,
                       const int* __restrict__ deg, const int* __restrict__ eidx,
                       const float* __restrict__ ss, float* __restrict__ h3_inout,
                       float* __restrict__ vbar) {
  const int n = blockIdx.x * 4 + (threadIdx.x >> 6);
  const int lane = threadIdx.x & 63;
  if (n >= NNODES) return;
  const int start = row_ptr[n], d = deg[n];
  const int j = lane * 2;
  const float sc0 = ss[j], sc1 = ss[j + 1];
  const float sh0 = ss[128 + j], sh1 = ss[129 + j];
  float a0 = 0.f, a1 = 0.f;
  int i = 0;
  for (; i + 2 <= d; i += 2) {
    int e0 = eidx[start + i], e1 = eidx[start + i + 1];
    float2 v0 = *(const float2*)(h3_inout + (size_t)e0 * DV + j);
    float2 v1 = *(const float2*)(h3_inout + (size_t)e1 * DV + j);
    float2 f0 = *(const float2*)(edge_fea + (size_t)e0 * DV + j);
    float2 f1 = *(const float2*)(edge_fea + (size_t)e1 * DV + j);
    a0 += v0.x + v1.x; a1 += v0.y + v1.y;
    float2 o0, o1;
    o0.x = f0.x + fmaf(v0.x, sc0, sh0); o0.y = f0.y + fmaf(v0.y, sc1, sh1);
    o1.x = f1.x + fmaf(v1.x, sc0, sh0); o1.y = f1.y + fmaf(v1.y, sc1, sh1);
    *(float2*)(h3_inout + (size_t)e0 * DV + j) = o0;
    *(float2*)(h3_inout + (size_t)e1 * DV + j) = o1;
  }
  if (i < d) {
    int e0 = eidx[start + i];
    float2 v0 = *(const float2*)(h3_inout + (size_t)e0 * DV + j);
    float2 f0 = *(const float2*)(edge_fea + (size_t)e0 * DV + j);
    a0 += v0.x; a1 += v0.y;
    float2 o0;
    o0.x = f0.x + fmaf(v0.x, sc0, sh0); o0.y = f0.y + fmaf(v0.y, sc1, sh1);
    *(float2*)(h3_inout + (size_t)e0 * DV + j) = o0;
  }
  float2 o;
  if (d > 0) {
    float inv = 1.f / (float)d;
    o.x = fmaf(a0 * inv, sc0, sh0);
    o.y = fmaf(a1 * inv, sc1, sh1);
  } else {
    o.x = 0.f; o.y = 0.f;
  }
  *(float2*)(vbar + (size_t)n * DV + j) = o;
}

// ---- node MLP (unchanged 32-row structure from round 4) ----
template<int K>
__device__ __forceinline__ void layer_mfma(const char* Als, const s16x8* __restrict__ Wp,
                                           f32x4 acc[4], int lane, int rg, int nh) {
  const int arow = rg * 16 + (lane & 15);
  const int rowoff = arow * (K * 2);
  const int kg16 = (lane >> 4) * 16;
  const int sw = (arow & 7) << 4;
#pragma unroll
  for (int n = 0; n < 4; n++) acc[n] = 0.0f;
#pragma unroll 2
  for (int kk = 0; kk < K / 32; kk++) {
    s16x8 a = *(const s16x8*)(Als + rowoff + ((kk * 64 + kg16) ^ sw));
#pragma unroll
    for (int n = 0; n < 4; n++) {
      s16x8 b = Wp[(size_t)(kk * 8 + nh * 4 + n) * 64 + lane];
      acc[n] = __builtin_amdgcn_mfma_f32_16x16x32_bf16(a, b, acc[n], 0, 0, 0);
    }
  }
}

__device__ __forceinline__ void store_h_lds(char* H, const f32x4 acc[4],
                                            const float* __restrict__ bias,
                                            int lane, int rg, int nh) {
  const int col0 = lane & 15, lg = lane >> 4;
#pragma unroll
  for (int n = 0; n < 4; n++) {
    const int col = nh * 64 + n * 16 + col0;
    float bi = bias[col];
#pragma unroll
    for (int r = 0; r < 4; r++) {
      int row = rg * 16 + lg * 4 + r;
      float v = lrelu(acc[n][r] + bi);
      *(ushort_t*)(H + row * 256 + ((col * 2) ^ ((row & 7) << 4))) = (ushort_t)f2bf(v);
    }
  }
}

__global__ __launch_bounds__(256)
void node_mlp_mfma(const float* __restrict__ node_fea, const float* __restrict__ vbar,
                   const ushort_t* __restrict__ Wp1, const float* __restrict__ b1,
                   const ushort_t* __restrict__ Wp2, const float* __restrict__ b2,
                   const ushort_t* __restrict__ Wp3, const float* __restrict__ b3,
                   float* __restrict__ h_out, float* __restrict__ slots) {
  __shared__ __align__(16) char zsm[32 * 512];   // 16KB
  __shared__ __align__(16) char hb[32 * 256];    // 8KB
  const int tid = threadIdx.x;
  const int lane = tid & 63, wid = tid >> 6;
  const int rg = wid & 1, nh = wid >> 1;
  const int n0 = blockIdx.x * 32;

  for (int t = tid; t < 32 * 32; t += 256) {
    int e = t / 32, p = t % 32;
    int nr = n0 + e;
    s16x8 v;
    if (nr < NNODES) {
      const float* src = (p < 16) ? (vbar + (size_t)nr * DV + p * 8)
                                  : (node_fea + (size_t)nr * DV + (p - 16) * 8);
      float4 x0 = *(const float4*)src;
      float4 x1 = *(const float4*)(src + 4);
      v[0] = f2bf(x0.x); v[1] = f2bf(x0.y); v[2] = f2bf(x0.z); v[3] = f2bf(x0.w);
      v[4] = f2bf(x1.x); v[5] = f2bf(x1.y); v[6] = f2bf(x1.z); v[7] = f2bf(x1.w);
    } else {
      v = (s16x8)0;
    }
    *(s16x8*)(zsm + e * 512 + ((p * 16) ^ ((e & 7) << 4))) = v;
  }
  __syncthreads();

  f32x4 acc[4];

  layer_mfma<256>(zsm, (const s16x8*)Wp1, acc, lane, rg, nh);
  store_h_lds(hb, acc, b1, lane, rg, nh);
  __syncthreads();

  layer_mfma<128>(hb, (const s16x8*)Wp2, acc, lane, rg, nh);
  __syncthreads();
  store_h_lds(zsm, acc, b2, lane, rg, nh);
  __syncthreads();

  layer_mfma<128>(zsm, (const s16x8*)Wp3, acc, lane, rg, nh);

  const int col0 = lane & 15, lg = lane >> 4;
  float* ps = (float*)hb;
  float* pq = (float*)zsm;
#pragma unroll
  for (int n = 0; n < 4; n++) {
    const int col = nh * 64 + n * 16 + col0;
    float bi = b3[col];
    float s = 0.f, q = 0.f;
#pragma unroll
    for (int r = 0; r < 4; r++) {
      int row = rg * 16 + lg * 4 + r;
      int gr = n0 + row;
      if (gr < NNODES) {
        float v = acc[n][r] + bi;
        h_out[(size_t)gr * DV + col] = v;
        s += v; q += v * v;
      }
    }
    ps[(rg * 4 + lg) * DV + col] = s;
    pq[(rg * 4 + lg) * DV + col] = q;
  }
  __syncthreads();
  if (tid < 128) {
    float s = 0.f, q = 0.f;
#pragma unroll
    for (int g = 0; g < 8; g++) { s += ps[g * DV + tid]; q += pq[g * DV + tid]; }
    float* sl = slots + (size_t)(blockIdx.x % NSLOT_V) * 256;
    atomicAdd(sl + tid, s);
    atomicAdd(sl + 128 + tid, q);
  }
}

__global__ __launch_bounds__(256)
void stats_reduce(const float* __restrict__ slots, int nslot, float inv_n,
                  const float* __restrict__ gamma, const float* __restrict__ beta,
                  float* __restrict__ ss) {
  __shared__ float tot[256];
  const int j = threadIdx.x;
  float s = 0.f;
  for (int t = 0; t < nslot; t++) s += slots[(size_t)t * 256 + j];
  tot[j] = s;
  __syncthreads();
  if (j < 128) {
    float mean = tot[j] * inv_n;
    float var = tot[j + 128] * inv_n - mean * mean;
    float rs = rsqrtf(var + BN_EPS);
    float sc = gamma[j] * rs;
    ss[j] = sc;
    ss[128 + j] = beta[j] - mean * sc;
  }
}

__global__ __launch_bounds__(256)
void node_finalize(const float* __restrict__ node_fea, const float* __restrict__ ss,
                   float* __restrict__ h_inout) {
  const size_t base = (size_t)blockIdx.x * 1024 + threadIdx.x * 4;
  const int j = (int)(base & 127);
  float4 h = *(float4*)&h_inout[base];
  float4 nf = *(const float4*)&node_fea[base];
  float4 o;
  o.x = nf.x + fmaf(h.x, ss[j + 0], ss[128 + j + 0]);
  o.y = nf.y + fmaf(h.y, ss[j + 1], ss[128 + j + 1]);
  o.z = nf.z + fmaf(h.z, ss[j + 2], ss[128 + j + 2]);
  o.w = nf.w + fmaf(h.w, ss[j + 3], ss[128 + j + 3]);
  *(float4*)&h_inout[base] = o;
}

extern "C" void kernel_launch(void* const* d_in, const int* in_sizes, int n_in,
                              void* d_out, int out_size, void* d_ws, size_t ws_size,
                              hipStream_t stream) {
  const float* node_fea = (const float*)d_in[0];
  const float* edge_fea = (const float*)d_in[1];
  const int* idx1 = (const int*)d_in[2];
  const int* idx2 = (const int*)d_in[3];
  const float* We1 = (const float*)d_in[4];  const float* be1 = (const float*)d_in[5];
  const float* We2 = (const float*)d_in[6];  const float* be2 = (const float*)d_in[7];
  const float* We3 = (const float*)d_in[8];  const float* be3 = (const float*)d_in[9];
  const float* Wv1 = (const float*)d_in[10]; const float* bv1 = (const float*)d_in[11];
  const float* Wv2 = (const float*)d_in[12]; const float* bv2 = (const float*)d_in[13];
  const float* Wv3 = (const float*)d_in[14]; const float* bv3 = (const float*)d_in[15];
  const float* gamma_e = (const float*)d_in[16]; const float* beta_e = (const float*)d_in[17];
  const float* gamma_v = (const float*)d_in[18]; const float* beta_v = (const float*)d_in[19];

  float* out_node = (float*)d_out;                     // [NNODES][128]
  float* out_edge = out_node + (size_t)NNODES * DV;    // [NEDGES][128]

  float* ws = (float*)d_ws;
  size_t o = 0;
  // zeroed region first: deg + BN slots
  int* deg = (int*)(ws + o);      o += NNODES;
  float* slots_e = ws + o;        o += (size_t)NSLOT_E * 256;
  float* slots_v = ws + o;        o += (size_t)NSLOT_V * 256;
  const size_t zero_bytes = o * sizeof(float);
  // non-zeroed scratch
  int* row_ptr = (int*)(ws + o);  o += NNODES;
  int* cursor = (int*)(ws + o);   o += NNODES;
  int* eidx = (int*)(ws + o);     o += NEDGES;
  float* vbar = ws + o;           o += (size_t)NNODES * DV;
  float* ss_e = ws + o;           o += 256;
  float* ss_v = ws + o;           o += 256;
  ushort_t* wpack = (ushort_t*)(ws + o);               // 288 frags * 512 ushort = 288KB

  const ushort_t* Wp_e1 = wpack;
  const ushort_t* Wp_e2 = wpack + (size_t)96 * 512;
  const ushort_t* Wp_e3 = wpack + (size_t)128 * 512;
  const ushort_t* Wp_v1 = wpack + (size_t)160 * 512;
  const ushort_t* Wp_v2 = wpack + (size_t)224 * 512;
  const ushort_t* Wp_v3 = wpack + (size_t)256 * 512;

  hipMemsetAsync(d_ws, 0, zero_bytes, stream);

  pack_all<<<72, 256, 0, stream>>>(We1, We2, We3, Wv1, Wv2, Wv3, wpack);
  csr_hist<<<(NEDGES + 255) / 256, 256, 0, stream>>>(idx1, deg);
  csr_scan<<<1, 256, 0, stream>>>(deg, row_ptr, cursor);
  csr_fill<<<(NEDGES + 255) / 256, 256, 0, stream>>>(idx1, cursor, eidx);

  edge_mlp_mfma<<<NEDGES / 64, 512, 0, stream>>>(node_fea, edge_fea, idx1, idx2,
                                                 Wp_e1, be1, Wp_e2, be2, Wp_e3, be3,
                                                 out_edge, slots_e);
  stats_reduce<<<1, 256, 0, stream>>>(slots_e, NSLOT_E, 1.f / NEDGES, gamma_e, beta_e, ss_e);
  node_gather_fused<<<(NNODES + 3) / 4, 256, 0, stream>>>(edge_fea, row_ptr, deg, eidx,
                                                          ss_e, out_edge, vbar);
  node_mlp_mfma<<<(NNODES + 31) / 32, 256, 0, stream>>>(node_fea, vbar,
                                                        Wp_v1, bv1, Wp_v2, bv2, Wp_v3, bv3,
                                                        out_node, slots_v);
  stats_reduce<<<1, 256, 0, stream>>>(slots_v, NSLOT_V, 1.f / NNODES, gamma_v, beta_v, ss_v);
  node_finalize<<<(NNODES * DV) / 1024, 256, 0, stream>>>(node_fea, ss_v, out_node);
}

// Round 6
// 861.158 us; speedup vs baseline: 4.4046x; 1.0893x over previous
//
#include <hip/hip_runtime.h>
#include <cstddef>

#define BN_EPS 1e-5f
constexpr int NNODES = 50000;
constexpr int NEDGES = 640000;
constexpr int DV = 128;
constexpr int NSLOT_E = 512;
constexpr int NSLOT_V = 256;

typedef __attribute__((ext_vector_type(4))) float f32x4;
typedef __attribute__((ext_vector_type(8))) short s16x8;
typedef unsigned short ushort_t;

__device__ __forceinline__ float lrelu(float x) { return x > 0.f ? x : 0.2f * x; }

__device__ __forceinline__ short f2bf(float f) {
  unsigned int u = __builtin_bit_cast(unsigned int, f);
  u += 0x7fffu + ((u >> 16) & 1u);   // round-to-nearest-even
  return (short)(u >> 16);
}

__device__ __forceinline__ float bf2f(ushort_t u) {
  return __builtin_bit_cast(float, (unsigned int)u << 16);
}

// ---- f32 -> bf16 bulk convert (8 values/thread) ----
__global__ __launch_bounds__(256)
void to_bf16(const float* __restrict__ src, ushort_t* __restrict__ dst, int n8) {
  int i = blockIdx.x * 256 + threadIdx.x;
  if (i >= n8) return;
  const float* s = src + (size_t)i * 8;
  float4 x0 = *(const float4*)s;
  float4 x1 = *(const float4*)(s + 4);
  s16x8 v;
  v[0] = f2bf(x0.x); v[1] = f2bf(x0.y); v[2] = f2bf(x0.z); v[3] = f2bf(x0.w);
  v[4] = f2bf(x1.x); v[5] = f2bf(x1.y); v[6] = f2bf(x1.z); v[7] = f2bf(x1.w);
  *(s16x8*)(dst + (size_t)i * 8) = v;
}

// ---- weight pre-pack: [K][128] f32 -> per-fragment bf16 layout ----
// frag (kk,n): lane holds B[k = kk*32 + (lane>>4)*8 + j][col = n*16 + (lane&15)], j=0..7
__global__ __launch_bounds__(256)
void pack_all(const float* __restrict__ W0, const float* __restrict__ W1,
              const float* __restrict__ W2, const float* __restrict__ W3,
              const float* __restrict__ W4, const float* __restrict__ W5,
              ushort_t* __restrict__ out) {
  int t = blockIdx.x * 256 + threadIdx.x;
  if (t >= 288 * 64) return;
  int lane = t & 63, f = t >> 6;
  const float* W; int lf;
  if (f < 96)       { W = W0; lf = f; }
  else if (f < 128) { W = W1; lf = f - 96; }
  else if (f < 160) { W = W2; lf = f - 128; }
  else if (f < 224) { W = W3; lf = f - 160; }
  else if (f < 256) { W = W4; lf = f - 224; }
  else              { W = W5; lf = f - 256; }
  int kk = lf >> 3, n = lf & 7;
  int k0 = kk * 32 + (lane >> 4) * 8, col = n * 16 + (lane & 15);
  s16x8 v;
#pragma unroll
  for (int j = 0; j < 8; j++) v[j] = f2bf(W[(size_t)(k0 + j) * DV + col]);
  *(s16x8*)(out + (size_t)t * 8) = v;
}

// ---- CSR build over idx1 ----
__global__ __launch_bounds__(256)
void csr_hist(const int* __restrict__ idx1, int* __restrict__ deg) {
  int e = blockIdx.x * 256 + threadIdx.x;
  if (e < NEDGES) atomicAdd(&deg[idx1[e]], 1);
}

__global__ __launch_bounds__(256)
void csr_scan(const int* __restrict__ deg, int* __restrict__ row_ptr,
              int* __restrict__ cursor) {
  __shared__ int part[256];
  const int t = threadIdx.x;
  const int CH = (NNODES + 255) / 256;
  int s = 0;
  for (int i = 0; i < CH; i++) { int n = t * CH + i; if (n < NNODES) s += deg[n]; }
  part[t] = s;
  __syncthreads();
  if (t == 0) {
    int run = 0;
    for (int i = 0; i < 256; i++) { int v = part[i]; part[i] = run; run += v; }
  }
  __syncthreads();
  int run = part[t];
  for (int i = 0; i < CH; i++) {
    int n = t * CH + i;
    if (n < NNODES) { row_ptr[n] = run; cursor[n] = run; run += deg[n]; }
  }
}

__global__ __launch_bounds__(256)
void csr_fill(const int* __restrict__ idx1, int* __restrict__ cursor,
              int* __restrict__ eidx) {
  int e = blockIdx.x * 256 + threadIdx.x;
  if (e < NEDGES) {
    int pos = atomicAdd(&cursor[idx1[e]], 1);
    eidx[pos] = e;
  }
}

// ---- MFMA span: wave covers 32 rows (rg half) x 32 cols (nh quarter) of 64-row tile.
template<int RS>  // LDS row stride in bytes
__device__ __forceinline__ void mfma_span(const char* Als, const s16x8* __restrict__ Wp,
                                          int fkk0, int nkk, f32x4 acc[2][2],
                                          int lane, int rg, int nh) {
  const int col0 = lane & 15;
  const int kg16 = (lane >> 4) * 16;
  const int sw = (col0 & 7) << 4;
  const int r0 = (rg * 32 + col0) * RS;
  const int r1 = (rg * 32 + 16 + col0) * RS;
#pragma unroll
  for (int kk = 0; kk < nkk; kk++) {
    const int ko = (kk * 64 + kg16) ^ sw;
    s16x8 a0 = *(const s16x8*)(Als + r0 + ko);
    s16x8 a1 = *(const s16x8*)(Als + r1 + ko);
    s16x8 b0 = Wp[(size_t)((fkk0 + kk) * 8 + nh * 2 + 0) * 64 + lane];
    s16x8 b1 = Wp[(size_t)((fkk0 + kk) * 8 + nh * 2 + 1) * 64 + lane];
    acc[0][0] = __builtin_amdgcn_mfma_f32_16x16x32_bf16(a0, b0, acc[0][0], 0, 0, 0);
    acc[0][1] = __builtin_amdgcn_mfma_f32_16x16x32_bf16(a0, b1, acc[0][1], 0, 0, 0);
    acc[1][0] = __builtin_amdgcn_mfma_f32_16x16x32_bf16(a1, b0, acc[1][0], 0, 0, 0);
    acc[1][1] = __builtin_amdgcn_mfma_f32_16x16x32_bf16(a1, b1, acc[1][1], 0, 0, 0);
  }
}

// bias + lrelu + bf16 -> swizzled LDS (row stride 256B), 64-row tile shape
__device__ __forceinline__ void store_h64(char* H, const f32x4 acc[2][2],
                                          const float* __restrict__ bias,
                                          int lane, int rg, int nh) {
  const int col0 = lane & 15, lg = lane >> 4;
#pragma unroll
  for (int ar = 0; ar < 2; ar++) {
#pragma unroll
    for (int n = 0; n < 2; n++) {
      const int col = nh * 32 + n * 16 + col0;
      float bi = bias[col];
#pragma unroll
      for (int r = 0; r < 4; r++) {
        int row = rg * 32 + ar * 16 + lg * 4 + r;
        float v = lrelu(acc[ar][n][r] + bi);
        *(ushort_t*)(H + row * 256 + ((col * 2) ^ ((row & 7) << 4))) = (ushort_t)f2bf(v);
      }
    }
  }
}

// h3 written as bf16 into the FIRST 256B of each edge's 512B out_edge slot
// (slot e = ushort offset e*256, cols 0..127)
__global__ __launch_bounds__(512, 8)
void edge_mlp_mfma(const ushort_t* __restrict__ node_b, const float* __restrict__ edge_fea,
                   const int* __restrict__ idx1, const int* __restrict__ idx2,
                   const ushort_t* __restrict__ Wp1, const float* __restrict__ b1,
                   const ushort_t* __restrict__ Wp2, const float* __restrict__ b2,
                   const ushort_t* __restrict__ Wp3, const float* __restrict__ b3,
                   ushort_t* __restrict__ h3b, float* __restrict__ slots) {
  __shared__ __align__(16) char zsm[64 * 384];   // 24KB: z K-half, later h2
  __shared__ __align__(16) char hb[64 * 256];    // 16KB: h1, later BN partials
  const int tid = threadIdx.x;
  const int lane = tid & 63, wid = tid >> 6;
  const int rg = wid & 1, nh = wid >> 1;
  const int e0 = blockIdx.x * 64;

  // ---- gather K-half A: cols 0..191 = [node1 bf16 x16ch | node2 bf16 cols0-63 x8ch]
  for (int t = tid; t < 64 * 24; t += 512) {
    int e = t / 24, p = t % 24;
    int er = e0 + e;
    const ushort_t* src = (p < 16) ? (node_b + (size_t)idx1[er] * DV + p * 8)
                                   : (node_b + (size_t)idx2[er] * DV + (p - 16) * 8);
    s16x8 v = *(const s16x8*)src;
    *(s16x8*)(zsm + e * 384 + ((p * 16) ^ ((e & 7) << 4))) = v;
  }
  __syncthreads();

  f32x4 acc[2][2];
#pragma unroll
  for (int i = 0; i < 2; i++)
#pragma unroll
    for (int j = 0; j < 2; j++) acc[i][j] = 0.0f;

  // ---- layer 1, k = 0..191
  mfma_span<384>(zsm, (const s16x8*)Wp1, 0, 6, acc, lane, rg, nh);
  __syncthreads();   // all zsm reads done before overwrite

  // ---- gather K-half B: cols 192..383 = [node2 cols64-127 x8ch | edge f32 x16ch]
  for (int t = tid; t < 64 * 24; t += 512) {
    int e = t / 24, p = t % 24;
    int er = e0 + e;
    s16x8 v;
    if (p < 8) {
      v = *(const s16x8*)(node_b + (size_t)idx2[er] * DV + 64 + p * 8);
    } else {
      const float* s = edge_fea + (size_t)er * DV + (p - 8) * 8;
      float4 x0 = *(const float4*)s;
      float4 x1 = *(const float4*)(s + 4);
      v[0] = f2bf(x0.x); v[1] = f2bf(x0.y); v[2] = f2bf(x0.z); v[3] = f2bf(x0.w);
      v[4] = f2bf(x1.x); v[5] = f2bf(x1.y); v[6] = f2bf(x1.z); v[7] = f2bf(x1.w);
    }
    *(s16x8*)(zsm + e * 384 + ((p * 16) ^ ((e & 7) << 4))) = v;
  }
  __syncthreads();

  // ---- layer 1, k = 192..383 (frags 6..11)
  mfma_span<384>(zsm, (const s16x8*)Wp1, 6, 6, acc, lane, rg, nh);

  store_h64(hb, acc, b1, lane, rg, nh);
  __syncthreads();

  // ---- layer 2 (reads hb)
#pragma unroll
  for (int i = 0; i < 2; i++)
#pragma unroll
    for (int j = 0; j < 2; j++) acc[i][j] = 0.0f;
  mfma_span<256>(hb, (const s16x8*)Wp2, 0, 4, acc, lane, rg, nh);

  store_h64(zsm, acc, b2, lane, rg, nh);
  __syncthreads();

  // ---- layer 3 (reads zsm)
#pragma unroll
  for (int i = 0; i < 2; i++)
#pragma unroll
    for (int j = 0; j < 2; j++) acc[i][j] = 0.0f;
  mfma_span<256>(zsm, (const s16x8*)Wp3, 0, 4, acc, lane, rg, nh);

  // ---- epilogue: bias, bf16 h3 -> slot, BN partials (f32, exact)
  const int col0 = lane & 15, lg = lane >> 4;
  float* ps = (float*)hb;            // [16][128] 8KB
  float* pq = ps + 16 * DV;          // [16][128] 8KB
#pragma unroll
  for (int ar = 0; ar < 2; ar++) {
#pragma unroll
    for (int n = 0; n < 2; n++) {
      const int col = nh * 32 + n * 16 + col0;
      float bi = b3[col];
      float s = 0.f, q = 0.f;
#pragma unroll
      for (int r = 0; r < 4; r++) {
        int row = rg * 32 + ar * 16 + lg * 4 + r;
        float v = acc[ar][n][r] + bi;
        h3b[(size_t)(e0 + row) * 256 + col] = (ushort_t)f2bf(v);
        s += v; q += v * v;
      }
      ps[(rg * 8 + ar * 4 + lg) * DV + col] = s;
      pq[(rg * 8 + ar * 4 + lg) * DV + col] = q;
    }
  }
  __syncthreads();
  if (tid < 128) {
    float s = 0.f, q = 0.f;
#pragma unroll
    for (int g = 0; g < 16; g++) { s += ps[g * DV + tid]; q += pq[g * DV + tid]; }
    float* sl = slots + (size_t)(blockIdx.x % NSLOT_E) * 256;
    atomicAdd(sl + tid, s);
    atomicAdd(sl + 128 + tid, q);
  }
}

// ---- per-node gather of bf16 h3 (in out_edge slots); finalizes out_edge f32 in place;
//      writes vbar (bf16) with sc/sh folded ----
__global__ __launch_bounds__(256)
void node_gather_fused(const float* __restrict__ edge_fea, const int* __restrict__ row_ptr,
                       const int* __restrict__ deg, const int* __restrict__ eidx,
                       const float* __restrict__ ss, float* eslot,
                       ushort_t* __restrict__ vbar_b) {
  const int n = blockIdx.x * 4 + (threadIdx.x >> 6);
  const int lane = threadIdx.x & 63;
  if (n >= NNODES) return;
  const int start = row_ptr[n], d = deg[n];
  const int j = lane * 2;
  const float sc0 = ss[j], sc1 = ss[j + 1];
  const float sh0 = ss[128 + j], sh1 = ss[129 + j];
  const ushort_t* h3b = (const ushort_t*)eslot;   // aliases eslot on purpose
  float a0 = 0.f, a1 = 0.f;
  int i = 0;
  for (; i + 2 <= d; i += 2) {
    int e0 = eidx[start + i], e1 = eidx[start + i + 1];
    ushort2 u0 = *(const ushort2*)(h3b + (size_t)e0 * 256 + j);
    ushort2 u1 = *(const ushort2*)(h3b + (size_t)e1 * 256 + j);
    float2 f0 = *(const float2*)(edge_fea + (size_t)e0 * DV + j);
    float2 f1 = *(const float2*)(edge_fea + (size_t)e1 * DV + j);
    float h00 = bf2f(u0.x), h01 = bf2f(u0.y);
    float h10 = bf2f(u1.x), h11 = bf2f(u1.y);
    a0 += h00 + h10; a1 += h01 + h11;
    float2 o0, o1;
    o0.x = f0.x + fmaf(h00, sc0, sh0); o0.y = f0.y + fmaf(h01, sc1, sh1);
    o1.x = f1.x + fmaf(h10, sc0, sh0); o1.y = f1.y + fmaf(h11, sc1, sh1);
    *(float2*)(eslot + (size_t)e0 * DV + j) = o0;
    *(float2*)(eslot + (size_t)e1 * DV + j) = o1;
  }
  if (i < d) {
    int e0 = eidx[start + i];
    ushort2 u0 = *(const ushort2*)(h3b + (size_t)e0 * 256 + j);
    float2 f0 = *(const float2*)(edge_fea + (size_t)e0 * DV + j);
    float h00 = bf2f(u0.x), h01 = bf2f(u0.y);
    a0 += h00; a1 += h01;
    float2 o0;
    o0.x = f0.x + fmaf(h00, sc0, sh0); o0.y = f0.y + fmaf(h01, sc1, sh1);
    *(float2*)(eslot + (size_t)e0 * DV + j) = o0;
  }
  float vx, vy;
  if (d > 0) {
    float inv = 1.f / (float)d;
    vx = fmaf(a0 * inv, sc0, sh0);
    vy = fmaf(a1 * inv, sc1, sh1);
  } else {
    vx = 0.f; vy = 0.f;
  }
  ushort2 vb;
  vb.x = (ushort_t)f2bf(vx);
  vb.y = (ushort_t)f2bf(vy);
  *(ushort2*)(vbar_b + (size_t)n * DV + j) = vb;
}

// ---- node MLP: 32-row tile, all-bf16 gather (pure copies) ----
template<int K>
__device__ __forceinline__ void layer_mfma(const char* Als, const s16x8* __restrict__ Wp,
                                           f32x4 acc[4], int lane, int rg, int nh) {
  const int arow = rg * 16 + (lane & 15);
  const int rowoff = arow * (K * 2);
  const int kg16 = (lane >> 4) * 16;
  const int sw = (arow & 7) << 4;
#pragma unroll
  for (int n = 0; n < 4; n++) acc[n] = 0.0f;
#pragma unroll 2
  for (int kk = 0; kk < K / 32; kk++) {
    s16x8 a = *(const s16x8*)(Als + rowoff + ((kk * 64 + kg16) ^ sw));
#pragma unroll
    for (int n = 0; n < 4; n++) {
      s16x8 b = Wp[(size_t)(kk * 8 + nh * 4 + n) * 64 + lane];
      acc[n] = __builtin_amdgcn_mfma_f32_16x16x32_bf16(a, b, acc[n], 0, 0, 0);
    }
  }
}

__device__ __forceinline__ void store_h_lds(char* H, const f32x4 acc[4],
                                            const float* __restrict__ bias,
                                            int lane, int rg, int nh) {
  const int col0 = lane & 15, lg = lane >> 4;
#pragma unroll
  for (int n = 0; n < 4; n++) {
    const int col = nh * 64 + n * 16 + col0;
    float bi = bias[col];
#pragma unroll
    for (int r = 0; r < 4; r++) {
      int row = rg * 16 + lg * 4 + r;
      float v = lrelu(acc[n][r] + bi);
      *(ushort_t*)(H + row * 256 + ((col * 2) ^ ((row & 7) << 4))) = (ushort_t)f2bf(v);
    }
  }
}

__global__ __launch_bounds__(256)
void node_mlp_mfma(const ushort_t* __restrict__ node_b, const ushort_t* __restrict__ vbar_b,
                   const ushort_t* __restrict__ Wp1, const float* __restrict__ b1,
                   const ushort_t* __restrict__ Wp2, const float* __restrict__ b2,
                   const ushort_t* __restrict__ Wp3, const float* __restrict__ b3,
                   float* __restrict__ h_out, float* __restrict__ slots) {
  __shared__ __align__(16) char zsm[32 * 512];   // 16KB
  __shared__ __align__(16) char hb[32 * 256];    // 8KB
  const int tid = threadIdx.x;
  const int lane = tid & 63, wid = tid >> 6;
  const int rg = wid & 1, nh = wid >> 1;
  const int n0 = blockIdx.x * 32;

  for (int t = tid; t < 32 * 32; t += 256) {
    int e = t / 32, p = t % 32;
    int nr = n0 + e;
    s16x8 v = (s16x8)0;
    if (nr < NNODES) {
      const ushort_t* src = (p < 16) ? (vbar_b + (size_t)nr * DV + p * 8)
                                     : (node_b + (size_t)nr * DV + (p - 16) * 8);
      v = *(const s16x8*)src;
    }
    *(s16x8*)(zsm + e * 512 + ((p * 16) ^ ((e & 7) << 4))) = v;
  }
  __syncthreads();

  f32x4 acc[4];

  layer_mfma<256>(zsm, (const s16x8*)Wp1, acc, lane, rg, nh);
  store_h_lds(hb, acc, b1, lane, rg, nh);
  __syncthreads();

  layer_mfma<128>(hb, (const s16x8*)Wp2, acc, lane, rg, nh);
  __syncthreads();
  store_h_lds(zsm, acc, b2, lane, rg, nh);
  __syncthreads();

  layer_mfma<128>(zsm, (const s16x8*)Wp3, acc, lane, rg, nh);

  const int col0 = lane & 15, lg = lane >> 4;
  float* ps = (float*)hb;
  float* pq = (float*)zsm;
#pragma unroll
  for (int n = 0; n < 4; n++) {
    const int col = nh * 64 + n * 16 + col0;
    float bi = b3[col];
    float s = 0.f, q = 0.f;
#pragma unroll
    for (int r = 0; r < 4; r++) {
      int row = rg * 16 + lg * 4 + r;
      int gr = n0 + row;
      if (gr < NNODES) {
        float v = acc[n][r] + bi;
        h_out[(size_t)gr * DV + col] = v;
        s += v; q += v * v;
      }
    }
    ps[(rg * 4 + lg) * DV + col] = s;
    pq[(rg * 4 + lg) * DV + col] = q;
  }
  __syncthreads();
  if (tid < 128) {
    float s = 0.f, q = 0.f;
#pragma unroll
    for (int g = 0; g < 8; g++) { s += ps[g * DV + tid]; q += pq[g * DV + tid]; }
    float* sl = slots + (size_t)(blockIdx.x % NSLOT_V) * 256;
    atomicAdd(sl + tid, s);
    atomicAdd(sl + 128 + tid, q);
  }
}

__global__ __launch_bounds__(256)
void stats_reduce(const float* __restrict__ slots, int nslot, float inv_n,
                  const float* __restrict__ gamma, const float* __restrict__ beta,
                  float* __restrict__ ss) {
  __shared__ float tot[256];
  const int j = threadIdx.x;
  float s = 0.f;
  for (int t = 0; t < nslot; t++) s += slots[(size_t)t * 256 + j];
  tot[j] = s;
  __syncthreads();
  if (j < 128) {
    float mean = tot[j] * inv_n;
    float var = tot[j + 128] * inv_n - mean * mean;
    float rs = rsqrtf(var + BN_EPS);
    float sc = gamma[j] * rs;
    ss[j] = sc;
    ss[128 + j] = beta[j] - mean * sc;
  }
}

__global__ __launch_bounds__(256)
void node_finalize(const float* __restrict__ node_fea, const float* __restrict__ ss,
                   float* __restrict__ h_inout) {
  const size_t base = (size_t)blockIdx.x * 1024 + threadIdx.x * 4;
  const int j = (int)(base & 127);
  float4 h = *(float4*)&h_inout[base];
  float4 nf = *(const float4*)&node_fea[base];
  float4 o;
  o.x = nf.x + fmaf(h.x, ss[j + 0], ss[128 + j + 0]);
  o.y = nf.y + fmaf(h.y, ss[j + 1], ss[128 + j + 1]);
  o.z = nf.z + fmaf(h.z, ss[j + 2], ss[128 + j + 2]);
  o.w = nf.w + fmaf(h.w, ss[j + 3], ss[128 + j + 3]);
  *(float4*)&h_inout[base] = o;
}

extern "C" void kernel_launch(void* const* d_in, const int* in_sizes, int n_in,
                              void* d_out, int out_size, void* d_ws, size_t ws_size,
                              hipStream_t stream) {
  const float* node_fea = (const float*)d_in[0];
  const float* edge_fea = (const float*)d_in[1];
  const int* idx1 = (const int*)d_in[2];
  const int* idx2 = (const int*)d_in[3];
  const float* We1 = (const float*)d_in[4];  const float* be1 = (const float*)d_in[5];
  const float* We2 = (const float*)d_in[6];  const float* be2 = (const float*)d_in[7];
  const float* We3 = (const float*)d_in[8];  const float* be3 = (const float*)d_in[9];
  const float* Wv1 = (const float*)d_in[10]; const float* bv1 = (const float*)d_in[11];
  const float* Wv2 = (const float*)d_in[12]; const float* bv2 = (const float*)d_in[13];
  const float* Wv3 = (const float*)d_in[14]; const float* bv3 = (const float*)d_in[15];
  const float* gamma_e = (const float*)d_in[16]; const float* beta_e = (const float*)d_in[17];
  const float* gamma_v = (const float*)d_in[18]; const float* beta_v = (const float*)d_in[19];

  float* out_node = (float*)d_out;                     // [NNODES][128]
  float* out_edge = out_node + (size_t)NNODES * DV;    // [NEDGES][128] (also h3b slots)

  float* ws = (float*)d_ws;
  size_t o = 0;
  // zeroed region first: deg + BN slots
  int* deg = (int*)(ws + o);      o += NNODES;
  float* slots_e = ws + o;        o += (size_t)NSLOT_E * 256;
  float* slots_v = ws + o;        o += (size_t)NSLOT_V * 256;
  const size_t zero_bytes = o * sizeof(float);
  // non-zeroed scratch
  int* row_ptr = (int*)(ws + o);  o += NNODES;
  int* cursor = (int*)(ws + o);   o += NNODES;
  int* eidx = (int*)(ws + o);     o += NEDGES;
  float* ss_e = ws + o;           o += 256;
  float* ss_v = ws + o;           o += 256;
  ushort_t* node_b = (ushort_t*)(ws + o);  o += (size_t)NNODES * DV / 2;  // bf16 nodes
  ushort_t* vbar_b = (ushort_t*)(ws + o);  o += (size_t)NNODES * DV / 2;  // bf16 vbar
  ushort_t* wpack = (ushort_t*)(ws + o);   // 288 frags * 512 ushort = 288KB

  const ushort_t* Wp_e1 = wpack;
  const ushort_t* Wp_e2 = wpack + (size_t)96 * 512;
  const ushort_t* Wp_e3 = wpack + (size_t)128 * 512;
  const ushort_t* Wp_v1 = wpack + (size_t)160 * 512;
  const ushort_t* Wp_v2 = wpack + (size_t)224 * 512;
  const ushort_t* Wp_v3 = wpack + (size_t)256 * 512;

  hipMemsetAsync(d_ws, 0, zero_bytes, stream);

  to_bf16<<<(NNODES * DV / 8 + 255) / 256, 256, 0, stream>>>(node_fea, node_b, NNODES * DV / 8);
  pack_all<<<72, 256, 0, stream>>>(We1, We2, We3, Wv1, Wv2, Wv3, wpack);
  csr_hist<<<(NEDGES + 255) / 256, 256, 0, stream>>>(idx1, deg);
  csr_scan<<<1, 256, 0, stream>>>(deg, row_ptr, cursor);
  csr_fill<<<(NEDGES + 255) / 256, 256, 0, stream>>>(idx1, cursor, eidx);

  edge_mlp_mfma<<<NEDGES / 64, 512, 0, stream>>>(node_b, edge_fea, idx1, idx2,
                                                 Wp_e1, be1, Wp_e2, be2, Wp_e3, be3,
                                                 (ushort_t*)out_edge, slots_e);
  stats_reduce<<<1, 256, 0, stream>>>(slots_e, NSLOT_E, 1.f / NEDGES, gamma_e, beta_e, ss_e);
  node_gather_fused<<<(NNODES + 3) / 4, 256, 0, stream>>>(edge_fea, row_ptr, deg, eidx,
                                                          ss_e, out_edge, vbar_b);
  node_mlp_mfma<<<(NNODES + 31) / 32, 256, 0, stream>>>(node_b, vbar_b,
                                                        Wp_v1, bv1, Wp_v2, bv2, Wp_v3, bv3,
                                                        out_node, slots_v);
  stats_reduce<<<1, 256, 0, stream>>>(slots_v, NSLOT_V, 1.f / NNODES, gamma_v, beta_v, ss_v);
  node_finalize<<<(NNODES * DV) / 1024, 256, 0, stream>>>(node_fea, ss_v, out_node);
}

// Round 7
// 859.658 us; speedup vs baseline: 4.4123x; 1.0017x over previous
//
#include <hip/hip_runtime.h>
#include <cstddef>

#define BN_EPS 1e-5f
constexpr int NNODES = 50000;
constexpr int NEDGES = 640000;
constexpr int DV = 128;
constexpr int NSLOT_E = 512;
constexpr int NSLOT_V = 256;

typedef __attribute__((ext_vector_type(4))) float f32x4;
typedef __attribute__((ext_vector_type(8))) short s16x8;
typedef unsigned short ushort_t;

__device__ __forceinline__ float lrelu(float x) { return x > 0.f ? x : 0.2f * x; }

// HW bf16 convert (RNE), gfx950 v_cvt_pk_bf16_f32
__device__ __forceinline__ unsigned cvt_pk_bf16(float lo, float hi) {
  unsigned r;
  asm("v_cvt_pk_bf16_f32 %0, %1, %2" : "=v"(r) : "v"(lo), "v"(hi));
  return r;
}
__device__ __forceinline__ ushort_t f2bf(float f) {
  unsigned r;
  asm("v_cvt_pk_bf16_f32 %0, %1, %1" : "=v"(r) : "v"(f));
  return (ushort_t)r;
}
__device__ __forceinline__ s16x8 pack8(float4 a, float4 b) {
  union { unsigned u[4]; s16x8 v; } r;
  r.u[0] = cvt_pk_bf16(a.x, a.y);
  r.u[1] = cvt_pk_bf16(a.z, a.w);
  r.u[2] = cvt_pk_bf16(b.x, b.y);
  r.u[3] = cvt_pk_bf16(b.z, b.w);
  return r.v;
}
__device__ __forceinline__ float bf2f(ushort_t u) {
  return __builtin_bit_cast(float, (unsigned int)u << 16);
}

// ---- f32 -> bf16 bulk convert (8 values/thread) ----
__global__ __launch_bounds__(256)
void to_bf16(const float* __restrict__ src, ushort_t* __restrict__ dst, int n8) {
  int i = blockIdx.x * 256 + threadIdx.x;
  if (i >= n8) return;
  const float* s = src + (size_t)i * 8;
  float4 x0 = *(const float4*)s;
  float4 x1 = *(const float4*)(s + 4);
  *(s16x8*)(dst + (size_t)i * 8) = pack8(x0, x1);
}

// ---- weight pre-pack: [K][128] f32 -> per-fragment bf16 layout ----
// frag (kk,n): lane holds B[k = kk*32 + (lane>>4)*8 + j][col = n*16 + (lane&15)], j=0..7
__global__ __launch_bounds__(256)
void pack_all(const float* __restrict__ W0, const float* __restrict__ W1,
              const float* __restrict__ W2, const float* __restrict__ W3,
              const float* __restrict__ W4, const float* __restrict__ W5,
              ushort_t* __restrict__ out) {
  int t = blockIdx.x * 256 + threadIdx.x;
  if (t >= 288 * 64) return;
  int lane = t & 63, f = t >> 6;
  const float* W; int lf;
  if (f < 96)       { W = W0; lf = f; }
  else if (f < 128) { W = W1; lf = f - 96; }
  else if (f < 160) { W = W2; lf = f - 128; }
  else if (f < 224) { W = W3; lf = f - 160; }
  else if (f < 256) { W = W4; lf = f - 224; }
  else              { W = W5; lf = f - 256; }
  int kk = lf >> 3, n = lf & 7;
  int k0 = kk * 32 + (lane >> 4) * 8, col = n * 16 + (lane & 15);
  s16x8 v;
#pragma unroll
  for (int j = 0; j < 8; j++) v[j] = (short)f2bf(W[(size_t)(k0 + j) * DV + col]);
  *(s16x8*)(out + (size_t)t * 8) = v;
}

// ---- CSR build over idx1 ----
__global__ __launch_bounds__(256)
void csr_hist(const int* __restrict__ idx1, int* __restrict__ deg) {
  int e = blockIdx.x * 256 + threadIdx.x;
  if (e < NEDGES) atomicAdd(&deg[idx1[e]], 1);
}

__global__ __launch_bounds__(256)
void csr_scan(const int* __restrict__ deg, int* __restrict__ row_ptr,
              int* __restrict__ cursor) {
  __shared__ int part[256];
  const int t = threadIdx.x;
  const int CH = (NNODES + 255) / 256;
  int s = 0;
  for (int i = 0; i < CH; i++) { int n = t * CH + i; if (n < NNODES) s += deg[n]; }
  part[t] = s;
  __syncthreads();
  if (t == 0) {
    int run = 0;
    for (int i = 0; i < 256; i++) { int v = part[i]; part[i] = run; run += v; }
  }
  __syncthreads();
  int run = part[t];
  for (int i = 0; i < CH; i++) {
    int n = t * CH + i;
    if (n < NNODES) { row_ptr[n] = run; cursor[n] = run; run += deg[n]; }
  }
}

__global__ __launch_bounds__(256)
void csr_fill(const int* __restrict__ idx1, int* __restrict__ cursor,
              int* __restrict__ eidx) {
  int e = blockIdx.x * 256 + threadIdx.x;
  if (e < NEDGES) {
    int pos = atomicAdd(&cursor[idx1[e]], 1);
    eidx[pos] = e;
  }
}

// ---- MFMA span: wave covers 32 rows (rg half) x 32 cols (nh quarter) of 64-row tile.
template<int RS>  // LDS row stride in bytes
__device__ __forceinline__ void mfma_span(const char* Als, const s16x8* __restrict__ Wp,
                                          int fkk0, int nkk, f32x4 acc[2][2],
                                          int lane, int rg, int nh) {
  const int col0 = lane & 15;
  const int kg16 = (lane >> 4) * 16;
  const int sw = (col0 & 7) << 4;
  const int r0 = (rg * 32 + col0) * RS;
  const int r1 = (rg * 32 + 16 + col0) * RS;
#pragma unroll
  for (int kk = 0; kk < nkk; kk++) {
    const int ko = (kk * 64 + kg16) ^ sw;
    s16x8 a0 = *(const s16x8*)(Als + r0 + ko);
    s16x8 a1 = *(const s16x8*)(Als + r1 + ko);
    s16x8 b0 = Wp[(size_t)((fkk0 + kk) * 8 + nh * 2 + 0) * 64 + lane];
    s16x8 b1 = Wp[(size_t)((fkk0 + kk) * 8 + nh * 2 + 1) * 64 + lane];
    acc[0][0] = __builtin_amdgcn_mfma_f32_16x16x32_bf16(a0, b0, acc[0][0], 0, 0, 0);
    acc[0][1] = __builtin_amdgcn_mfma_f32_16x16x32_bf16(a0, b1, acc[0][1], 0, 0, 0);
    acc[1][0] = __builtin_amdgcn_mfma_f32_16x16x32_bf16(a1, b0, acc[1][0], 0, 0, 0);
    acc[1][1] = __builtin_amdgcn_mfma_f32_16x16x32_bf16(a1, b1, acc[1][1], 0, 0, 0);
  }
}

// bias + lrelu + bf16 -> swizzled LDS (row stride 256B), 64-row tile shape
__device__ __forceinline__ void store_h64(char* H, const f32x4 acc[2][2],
                                          const float* __restrict__ bias,
                                          int lane, int rg, int nh) {
  const int col0 = lane & 15, lg = lane >> 4;
#pragma unroll
  for (int ar = 0; ar < 2; ar++) {
#pragma unroll
    for (int n = 0; n < 2; n++) {
      const int col = nh * 32 + n * 16 + col0;
      float bi = bias[col];
#pragma unroll
      for (int r = 0; r < 4; r++) {
        int row = rg * 32 + ar * 16 + lg * 4 + r;
        float v = lrelu(acc[ar][n][r] + bi);
        *(ushort_t*)(H + row * 256 + ((col * 2) ^ ((row & 7) << 4))) = f2bf(v);
      }
    }
  }
}

// slot layout per edge (ushort units, stride 256): [0..127]=h3 bf16, [128..255]=edge_fea bf16
__global__ __launch_bounds__(512, 8)
void edge_mlp_mfma(const ushort_t* __restrict__ node_b, const float* __restrict__ edge_fea,
                   const int* __restrict__ idx1, const int* __restrict__ idx2,
                   const ushort_t* __restrict__ Wp1, const float* __restrict__ b1,
                   const ushort_t* __restrict__ Wp2, const float* __restrict__ b2,
                   const ushort_t* __restrict__ Wp3, const float* __restrict__ b3,
                   ushort_t* __restrict__ slot, float* __restrict__ slots) {
  __shared__ __align__(16) char zsm[64 * 384];   // 24KB: z K-half, later h2
  __shared__ __align__(16) char hb[64 * 256];    // 16KB: h1, later BN partials
  const int tid = threadIdx.x;
  const int lane = tid & 63, wid = tid >> 6;
  const int rg = wid & 1, nh = wid >> 1;
  const int e0 = blockIdx.x * 64;

  // ---- gather K-half A: cols 0..191 = [node1 bf16 x16ch | node2 bf16 cols0-63 x8ch]
  for (int t = tid; t < 64 * 24; t += 512) {
    int e = t / 24, p = t % 24;
    int er = e0 + e;
    const ushort_t* src = (p < 16) ? (node_b + (size_t)idx1[er] * DV + p * 8)
                                   : (node_b + (size_t)idx2[er] * DV + (p - 16) * 8);
    s16x8 v = *(const s16x8*)src;
    *(s16x8*)(zsm + e * 384 + ((p * 16) ^ ((e & 7) << 4))) = v;
  }
  __syncthreads();

  f32x4 acc[2][2];
#pragma unroll
  for (int i = 0; i < 2; i++)
#pragma unroll
    for (int j = 0; j < 2; j++) acc[i][j] = 0.0f;

  // ---- layer 1, k = 0..191
  mfma_span<384>(zsm, (const s16x8*)Wp1, 0, 6, acc, lane, rg, nh);
  __syncthreads();   // all zsm reads done before overwrite

  // ---- gather K-half B: cols 192..383 = [node2 cols64-127 x8ch | edge f32 x16ch]
  //      edge chunks additionally copied (bf16) into slot second half for the gather RMW
  for (int t = tid; t < 64 * 24; t += 512) {
    int e = t / 24, p = t % 24;
    int er = e0 + e;
    s16x8 v;
    if (p < 8) {
      v = *(const s16x8*)(node_b + (size_t)idx2[er] * DV + 64 + p * 8);
    } else {
      const float* s = edge_fea + (size_t)er * DV + (p - 8) * 8;
      float4 x0 = *(const float4*)s;
      float4 x1 = *(const float4*)(s + 4);
      v = pack8(x0, x1);
      *(s16x8*)(slot + (size_t)er * 256 + 128 + (p - 8) * 8) = v;
    }
    *(s16x8*)(zsm + e * 384 + ((p * 16) ^ ((e & 7) << 4))) = v;
  }
  __syncthreads();

  // ---- layer 1, k = 192..383 (frags 6..11)
  mfma_span<384>(zsm, (const s16x8*)Wp1, 6, 6, acc, lane, rg, nh);

  store_h64(hb, acc, b1, lane, rg, nh);
  __syncthreads();

  // ---- layer 2 (reads hb)
#pragma unroll
  for (int i = 0; i < 2; i++)
#pragma unroll
    for (int j = 0; j < 2; j++) acc[i][j] = 0.0f;
  mfma_span<256>(hb, (const s16x8*)Wp2, 0, 4, acc, lane, rg, nh);

  store_h64(zsm, acc, b2, lane, rg, nh);
  __syncthreads();

  // ---- layer 3 (reads zsm)
#pragma unroll
  for (int i = 0; i < 2; i++)
#pragma unroll
    for (int j = 0; j < 2; j++) acc[i][j] = 0.0f;
  mfma_span<256>(zsm, (const s16x8*)Wp3, 0, 4, acc, lane, rg, nh);

  // ---- epilogue: bias, bf16 h3 -> slot first half, BN partials (f32, exact)
  const int col0 = lane & 15, lg = lane >> 4;
  float* ps = (float*)hb;            // [16][128] 8KB
  float* pq = ps + 16 * DV;          // [16][128] 8KB
#pragma unroll
  for (int ar = 0; ar < 2; ar++) {
#pragma unroll
    for (int n = 0; n < 2; n++) {
      const int col = nh * 32 + n * 16 + col0;
      float bi = b3[col];
      float s = 0.f, q = 0.f;
#pragma unroll
      for (int r = 0; r < 4; r++) {
        int row = rg * 32 + ar * 16 + lg * 4 + r;
        float v = acc[ar][n][r] + bi;
        slot[(size_t)(e0 + row) * 256 + col] = f2bf(v);
        s += v; q += v * v;
      }
      ps[(rg * 8 + ar * 4 + lg) * DV + col] = s;
      pq[(rg * 8 + ar * 4 + lg) * DV + col] = q;
    }
  }
  __syncthreads();
  if (tid < 128) {
    float s = 0.f, q = 0.f;
#pragma unroll
    for (int g = 0; g < 16; g++) { s += ps[g * DV + tid]; q += pq[g * DV + tid]; }
    float* sl = slots + (size_t)(blockIdx.x % NSLOT_E) * 256;
    atomicAdd(sl + tid, s);
    atomicAdd(sl + 128 + tid, q);
  }
}

// ---- per-node gather: read each edge's 512B slot (h3|edge bf16), overwrite in place
//      with final f32 out_edge row; accumulate node mean -> vbar (bf16, sc/sh folded) ----
__global__ __launch_bounds__(256)
void node_gather_fused(const int* __restrict__ row_ptr, const int* __restrict__ deg,
                       const int* __restrict__ eidx, const float* __restrict__ ss,
                       float* eslot, ushort_t* __restrict__ vbar_b) {
  const int n = blockIdx.x * 4 + (threadIdx.x >> 6);
  const int lane = threadIdx.x & 63;
  if (n >= NNODES) return;
  const int start = row_ptr[n], d = deg[n];
  const int j = lane * 2;
  const float sc0 = ss[j], sc1 = ss[j + 1];
  const float sh0 = ss[128 + j], sh1 = ss[129 + j];
  const ushort_t* slot = (const ushort_t*)eslot;   // aliases eslot on purpose
  float a0 = 0.f, a1 = 0.f;
  int i = 0;
  for (; i + 2 <= d; i += 2) {
    int e0 = eidx[start + i], e1 = eidx[start + i + 1];
    ushort2 uh0 = *(const ushort2*)(slot + (size_t)e0 * 256 + j);
    ushort2 ue0 = *(const ushort2*)(slot + (size_t)e0 * 256 + 128 + j);
    ushort2 uh1 = *(const ushort2*)(slot + (size_t)e1 * 256 + j);
    ushort2 ue1 = *(const ushort2*)(slot + (size_t)e1 * 256 + 128 + j);
    float h00 = bf2f(uh0.x), h01 = bf2f(uh0.y);
    float h10 = bf2f(uh1.x), h11 = bf2f(uh1.y);
    a0 += h00 + h10; a1 += h01 + h11;
    float2 o0, o1;
    o0.x = bf2f(ue0.x) + fmaf(h00, sc0, sh0); o0.y = bf2f(ue0.y) + fmaf(h01, sc1, sh1);
    o1.x = bf2f(ue1.x) + fmaf(h10, sc0, sh0); o1.y = bf2f(ue1.y) + fmaf(h11, sc1, sh1);
    *(float2*)(eslot + (size_t)e0 * DV + j) = o0;
    *(float2*)(eslot + (size_t)e1 * DV + j) = o1;
  }
  if (i < d) {
    int e0 = eidx[start + i];
    ushort2 uh0 = *(const ushort2*)(slot + (size_t)e0 * 256 + j);
    ushort2 ue0 = *(const ushort2*)(slot + (size_t)e0 * 256 + 128 + j);
    float h00 = bf2f(uh0.x), h01 = bf2f(uh0.y);
    a0 += h00; a1 += h01;
    float2 o0;
    o0.x = bf2f(ue0.x) + fmaf(h00, sc0, sh0); o0.y = bf2f(ue0.y) + fmaf(h01, sc1, sh1);
    *(float2*)(eslot + (size_t)e0 * DV + j) = o0;
  }
  float vx, vy;
  if (d > 0) {
    float inv = 1.f / (float)d;
    vx = fmaf(a0 * inv, sc0, sh0);
    vy = fmaf(a1 * inv, sc1, sh1);
  } else {
    vx = 0.f; vy = 0.f;
  }
  unsigned vb = cvt_pk_bf16(vx, vy);
  *(unsigned*)(vbar_b + (size_t)n * DV + j) = vb;
}

// ---- node MLP: 32-row tile, all-bf16 gather (pure copies) ----
template<int K>
__device__ __forceinline__ void layer_mfma(const char* Als, const s16x8* __restrict__ Wp,
                                           f32x4 acc[4], int lane, int rg, int nh) {
  const int arow = rg * 16 + (lane & 15);
  const int rowoff = arow * (K * 2);
  const int kg16 = (lane >> 4) * 16;
  const int sw = (arow & 7) << 4;
#pragma unroll
  for (int n = 0; n < 4; n++) acc[n] = 0.0f;
#pragma unroll 2
  for (int kk = 0; kk < K / 32; kk++) {
    s16x8 a = *(const s16x8*)(Als + rowoff + ((kk * 64 + kg16) ^ sw));
#pragma unroll
    for (int n = 0; n < 4; n++) {
      s16x8 b = Wp[(size_t)(kk * 8 + nh * 4 + n) * 64 + lane];
      acc[n] = __builtin_amdgcn_mfma_f32_16x16x32_bf16(a, b, acc[n], 0, 0, 0);
    }
  }
}

__device__ __forceinline__ void store_h_lds(char* H, const f32x4 acc[4],
                                            const float* __restrict__ bias,
                                            int lane, int rg, int nh) {
  const int col0 = lane & 15, lg = lane >> 4;
#pragma unroll
  for (int n = 0; n < 4; n++) {
    const int col = nh * 64 + n * 16 + col0;
    float bi = bias[col];
#pragma unroll
    for (int r = 0; r < 4; r++) {
      int row = rg * 16 + lg * 4 + r;
      float v = lrelu(acc[n][r] + bi);
      *(ushort_t*)(H + row * 256 + ((col * 2) ^ ((row & 7) << 4))) = f2bf(v);
    }
  }
}

__global__ __launch_bounds__(256)
void node_mlp_mfma(const ushort_t* __restrict__ node_b, const ushort_t* __restrict__ vbar_b,
                   const ushort_t* __restrict__ Wp1, const float* __restrict__ b1,
                   const ushort_t* __restrict__ Wp2, const float* __restrict__ b2,
                   const ushort_t* __restrict__ Wp3, const float* __restrict__ b3,
                   float* __restrict__ h_out, float* __restrict__ slots) {
  __shared__ __align__(16) char zsm[32 * 512];   // 16KB
  __shared__ __align__(16) char hb[32 * 256];    // 8KB
  const int tid = threadIdx.x;
  const int lane = tid & 63, wid = tid >> 6;
  const int rg = wid & 1, nh = wid >> 1;
  const int n0 = blockIdx.x * 32;

  for (int t = tid; t < 32 * 32; t += 256) {
    int e = t / 32, p = t % 32;
    int nr = n0 + e;
    s16x8 v = (s16x8)0;
    if (nr < NNODES) {
      const ushort_t* src = (p < 16) ? (vbar_b + (size_t)nr * DV + p * 8)
                                     : (node_b + (size_t)nr * DV + (p - 16) * 8);
      v = *(const s16x8*)src;
    }
    *(s16x8*)(zsm + e * 512 + ((p * 16) ^ ((e & 7) << 4))) = v;
  }
  __syncthreads();

  f32x4 acc[4];

  layer_mfma<256>(zsm, (const s16x8*)Wp1, acc, lane, rg, nh);
  store_h_lds(hb, acc, b1, lane, rg, nh);
  __syncthreads();

  layer_mfma<128>(hb, (const s16x8*)Wp2, acc, lane, rg, nh);
  __syncthreads();
  store_h_lds(zsm, acc, b2, lane, rg, nh);
  __syncthreads();

  layer_mfma<128>(zsm, (const s16x8*)Wp3, acc, lane, rg, nh);

  const int col0 = lane & 15, lg = lane >> 4;
  float* ps = (float*)hb;
  float* pq = (float*)zsm;
#pragma unroll
  for (int n = 0; n < 4; n++) {
    const int col = nh * 64 + n * 16 + col0;
    float bi = b3[col];
    float s = 0.f, q = 0.f;
#pragma unroll
    for (int r = 0; r < 4; r++) {
      int row = rg * 16 + lg * 4 + r;
      int gr = n0 + row;
      if (gr < NNODES) {
        float v = acc[n][r] + bi;
        h_out[(size_t)gr * DV + col] = v;
        s += v; q += v * v;
      }
    }
    ps[(rg * 4 + lg) * DV + col] = s;
    pq[(rg * 4 + lg) * DV + col] = q;
  }
  __syncthreads();
  if (tid < 128) {
    float s = 0.f, q = 0.f;
#pragma unroll
    for (int g = 0; g < 8; g++) { s += ps[g * DV + tid]; q += pq[g * DV + tid]; }
    float* sl = slots + (size_t)(blockIdx.x % NSLOT_V) * 256;
    atomicAdd(sl + tid, s);
    atomicAdd(sl + 128 + tid, q);
  }
}

__global__ __launch_bounds__(256)
void stats_reduce(const float* __restrict__ slots, int nslot, float inv_n,
                  const float* __restrict__ gamma, const float* __restrict__ beta,
                  float* __restrict__ ss) {
  __shared__ float tot[256];
  const int j = threadIdx.x;
  float s = 0.f;
  for (int t = 0; t < nslot; t++) s += slots[(size_t)t * 256 + j];
  tot[j] = s;
  __syncthreads();
  if (j < 128) {
    float mean = tot[j] * inv_n;
    float var = tot[j + 128] * inv_n - mean * mean;
    float rs = rsqrtf(var + BN_EPS);
    float sc = gamma[j] * rs;
    ss[j] = sc;
    ss[128 + j] = beta[j] - mean * sc;
  }
}

__global__ __launch_bounds__(256)
void node_finalize(const float* __restrict__ node_fea, const float* __restrict__ ss,
                   float* __restrict__ h_inout) {
  const size_t base = (size_t)blockIdx.x * 1024 + threadIdx.x * 4;
  const int j = (int)(base & 127);
  float4 h = *(float4*)&h_inout[base];
  float4 nf = *(const float4*)&node_fea[base];
  float4 o;
  o.x = nf.x + fmaf(h.x, ss[j + 0], ss[128 + j + 0]);
  o.y = nf.y + fmaf(h.y, ss[j + 1], ss[128 + j + 1]);
  o.z = nf.z + fmaf(h.z, ss[j + 2], ss[128 + j + 2]);
  o.w = nf.w + fmaf(h.w, ss[j + 3], ss[128 + j + 3]);
  *(float4*)&h_inout[base] = o;
}

extern "C" void kernel_launch(void* const* d_in, const int* in_sizes, int n_in,
                              void* d_out, int out_size, void* d_ws, size_t ws_size,
                              hipStream_t stream) {
  const float* node_fea = (const float*)d_in[0];
  const float* edge_fea = (const float*)d_in[1];
  const int* idx1 = (const int*)d_in[2];
  const int* idx2 = (const int*)d_in[3];
  const float* We1 = (const float*)d_in[4];  const float* be1 = (const float*)d_in[5];
  const float* We2 = (const float*)d_in[6];  const float* be2 = (const float*)d_in[7];
  const float* We3 = (const float*)d_in[8];  const float* be3 = (const float*)d_in[9];
  const float* Wv1 = (const float*)d_in[10]; const float* bv1 = (const float*)d_in[11];
  const float* Wv2 = (const float*)d_in[12]; const float* bv2 = (const float*)d_in[13];
  const float* Wv3 = (const float*)d_in[14]; const float* bv3 = (const float*)d_in[15];
  const float* gamma_e = (const float*)d_in[16]; const float* beta_e = (const float*)d_in[17];
  const float* gamma_v = (const float*)d_in[18]; const float* beta_v = (const float*)d_in[19];

  float* out_node = (float*)d_out;                     // [NNODES][128]
  float* out_edge = out_node + (size_t)NNODES * DV;    // [NEDGES][128] (also bf16 slots)

  float* ws = (float*)d_ws;
  size_t o = 0;
  // zeroed region first: deg + BN slots
  int* deg = (int*)(ws + o);      o += NNODES;
  float* slots_e = ws + o;        o += (size_t)NSLOT_E * 256;
  float* slots_v = ws + o;        o += (size_t)NSLOT_V * 256;
  const size_t zero_bytes = o * sizeof(float);
  // non-zeroed scratch
  int* row_ptr = (int*)(ws + o);  o += NNODES;
  int* cursor = (int*)(ws + o);   o += NNODES;
  int* eidx = (int*)(ws + o);     o += NEDGES;
  float* ss_e = ws + o;           o += 256;
  float* ss_v = ws + o;           o += 256;
  ushort_t* node_b = (ushort_t*)(ws + o);  o += (size_t)NNODES * DV / 2;  // bf16 nodes
  ushort_t* vbar_b = (ushort_t*)(ws + o);  o += (size_t)NNODES * DV / 2;  // bf16 vbar
  ushort_t* wpack = (ushort_t*)(ws + o);   // 288 frags * 512 ushort = 288KB

  const ushort_t* Wp_e1 = wpack;
  const ushort_t* Wp_e2 = wpack + (size_t)96 * 512;
  const ushort_t* Wp_e3 = wpack + (size_t)128 * 512;
  const ushort_t* Wp_v1 = wpack + (size_t)160 * 512;
  const ushort_t* Wp_v2 = wpack + (size_t)224 * 512;
  const ushort_t* Wp_v3 = wpack + (size_t)256 * 512;

  hipMemsetAsync(d_ws, 0, zero_bytes, stream);

  to_bf16<<<(NNODES * DV / 8 + 255) / 256, 256, 0, stream>>>(node_fea, node_b, NNODES * DV / 8);
  pack_all<<<72, 256, 0, stream>>>(We1, We2, We3, Wv1, Wv2, Wv3, wpack);
  csr_hist<<<(NEDGES + 255) / 256, 256, 0, stream>>>(idx1, deg);
  csr_scan<<<1, 256, 0, stream>>>(deg, row_ptr, cursor);
  csr_fill<<<(NEDGES + 255) / 256, 256, 0, stream>>>(idx1, cursor, eidx);

  edge_mlp_mfma<<<NEDGES / 64, 512, 0, stream>>>(node_b, edge_fea, idx1, idx2,
                                                 Wp_e1, be1, Wp_e2, be2, Wp_e3, be3,
                                                 (ushort_t*)out_edge, slots_e);
  stats_reduce<<<1, 256, 0, stream>>>(slots_e, NSLOT_E, 1.f / NEDGES, gamma_e, beta_e, ss_e);
  node_gather_fused<<<(NNODES + 3) / 4, 256, 0, stream>>>(row_ptr, deg, eidx,
                                                          ss_e, out_edge, vbar_b);
  node_mlp_mfma<<<(NNODES + 31) / 32, 256, 0, stream>>>(node_b, vbar_b,
                                                        Wp_v1, bv1, Wp_v2, bv2, Wp_v3, bv3,
                                                        out_node, slots_v);
  stats_reduce<<<1, 256, 0, stream>>>(slots_v, NSLOT_V, 1.f / NNODES, gamma_v, beta_v, ss_v);
  node_finalize<<<(NNODES * DV) / 1024, 256, 0, stream>>>(node_fea, ss_v, out_node);
}